// Round 4
// baseline (204.093 us; speedup 1.0000x reference)
//
#include <hip/hip_runtime.h>

// Inputs and outputs are float32 (established R1/R3).
#define NCLS 91
#define W1_LD 2052   // repn_w1 row length (2C+4)

typedef __attribute__((ext_vector_type(8))) short short8;   // 8 bf16 (4 VGPRs)
typedef __attribute__((ext_vector_type(4))) float f32x4;    // MFMA C/D

__device__ inline ushort bf16_rne(float x) {
    unsigned u = __float_as_uint(x);
    return (ushort)((u + 0x7fffu + ((u >> 16) & 1u)) >> 16);
}

// ---------- K1: p_part[z][i][r] = feats[i, z*128:+128] . Wcomb[r, z*128:+128] ----------
// Wcomb rows 0..255 = wf1, 256..511 = wf2. grid (8 r-tiles, 16 i-tiles, 8 z), 128 thr.
// z=8 K-split: 1024 blocks -> 4 blocks/CU, 8 waves/CU in 4 independent barrier groups.
__global__ __launch_bounds__(128) void k_p12(const float* __restrict__ feats,
                                             const float* __restrict__ w1f,
                                             float* __restrict__ pp) {
    int r0 = blockIdx.x * 64, i0 = blockIdx.y * 32, z = blockIdx.z;
    int tid = threadIdx.x, tx = tid & 15, ty = tid >> 4;
    __shared__ float As[64 * 32];   // [k][i]
    __shared__ float Bs[64 * 64];   // [k][r]
    float* pout = pp + z * 262144;
    int ai = tid & 31, akq = (tid >> 5) * 16;          // A loader: 4 float4 along k
    int br = tid & 63, bkq = (tid >> 6) * 32;          // B loader: 8 float4 along k
    const float* abase = feats + (i0 + ai) * 1024 + z * 128 + akq;
    int rg = r0 + br;
    const float* bbase = w1f + (rg < 256 ? rg * W1_LD : (rg - 256) * W1_LD + 1024)
                       + z * 128 + bkq;
    float4 av[4], bv[8];
#pragma unroll
    for (int s = 0; s < 4; ++s) av[s] = *(const float4*)(abase + 4 * s);
#pragma unroll
    for (int s = 0; s < 8; ++s) bv[s] = *(const float4*)(bbase + 4 * s);
    float acc[4][4] = {};
    for (int kt = 0; kt < 2; ++kt) {
#pragma unroll
        for (int s = 0; s < 4; ++s) {   // transpose store: lanes distinct ai -> 2-way max
            int k = akq + 4 * s;
            As[(k + 0) * 32 + ai] = av[s].x; As[(k + 1) * 32 + ai] = av[s].y;
            As[(k + 2) * 32 + ai] = av[s].z; As[(k + 3) * 32 + ai] = av[s].w;
        }
#pragma unroll
        for (int s = 0; s < 8; ++s) {   // transpose store: lanes distinct br -> 2-way max
            int k = bkq + 4 * s;
            Bs[(k + 0) * 64 + br] = bv[s].x; Bs[(k + 1) * 64 + br] = bv[s].y;
            Bs[(k + 2) * 64 + br] = bv[s].z; Bs[(k + 3) * 64 + br] = bv[s].w;
        }
        __syncthreads();
        if (kt + 1 < 2) {
#pragma unroll
            for (int s = 0; s < 4; ++s) av[s] = *(const float4*)(abase + 64 + 4 * s);
#pragma unroll
            for (int s = 0; s < 8; ++s) bv[s] = *(const float4*)(bbase + 64 + 4 * s);
        }
#pragma unroll
        for (int k = 0; k < 64; ++k) {
            float4 a4 = *(const float4*)(As + k * 32 + ty * 4);
            float4 b4 = *(const float4*)(Bs + k * 64 + tx * 4);
            acc[0][0] = fmaf(a4.x, b4.x, acc[0][0]); acc[0][1] = fmaf(a4.x, b4.y, acc[0][1]);
            acc[0][2] = fmaf(a4.x, b4.z, acc[0][2]); acc[0][3] = fmaf(a4.x, b4.w, acc[0][3]);
            acc[1][0] = fmaf(a4.y, b4.x, acc[1][0]); acc[1][1] = fmaf(a4.y, b4.y, acc[1][1]);
            acc[1][2] = fmaf(a4.y, b4.z, acc[1][2]); acc[1][3] = fmaf(a4.y, b4.w, acc[1][3]);
            acc[2][0] = fmaf(a4.z, b4.x, acc[2][0]); acc[2][1] = fmaf(a4.z, b4.y, acc[2][1]);
            acc[2][2] = fmaf(a4.z, b4.z, acc[2][2]); acc[2][3] = fmaf(a4.z, b4.w, acc[2][3]);
            acc[3][0] = fmaf(a4.w, b4.x, acc[3][0]); acc[3][1] = fmaf(a4.w, b4.y, acc[3][1]);
            acc[3][2] = fmaf(a4.w, b4.z, acc[3][2]); acc[3][3] = fmaf(a4.w, b4.w, acc[3][3]);
        }
        __syncthreads();
    }
#pragma unroll
    for (int ii = 0; ii < 4; ++ii)
        *(float4*)(pout + (i0 + ty * 4 + ii) * 512 + r0 + tx * 4) =
            make_float4(acc[ii][0], acc[ii][1], acc[ii][2], acc[ii][3]);
}

// ---------- K2: rel partials, h-chunk split 4-way across z ----------
// grid (8 j, 32 i, 4 z), 256 thr -> 1024 blocks, 4 blocks/CU, 16 waves/CU.
// z handles ch = z*2 .. z*2+1 (h rows z*64..+64). Staging sums the 8 pp K-partials.
// z=0 partial -> r0 (rel_out scratch), z>0 -> prel[z-1]. Final sum + b2 in k_topk.
__global__ __launch_bounds__(256) void k_rel(const float* __restrict__ pp,
                                             const float* __restrict__ w1f,
                                             const float* __restrict__ b1f,
                                             const float* __restrict__ w2f,
                                             const float* __restrict__ boxesf,
                                             float* __restrict__ r0,
                                             float* __restrict__ prel) {
    int j0 = blockIdx.x * 64, i0 = blockIdx.y * 16, z = blockIdx.z;
    int tid = threadIdx.x, tx = tid & 63, ty = tid >> 6;
    __shared__ float As1[32 * 17];  // [h][i] pad 17
    __shared__ float Bs[32 * 64];   // [h][j]
    __shared__ float Awg[32 * 4];
    __shared__ float Aw2[32];
    float4 bj = *(const float4*)(boxesf + (j0 + tx) * 4);
    float g[4][4];
#pragma unroll
    for (int s = 0; s < 4; ++s) {
        float4 bi = *(const float4*)(boxesf + (i0 + ty * 4 + s) * 4);
        g[s][0] = fabsf(bi.x - bj.x); g[s][1] = fabsf(bi.y - bj.y);
        g[s][2] = fabsf(bi.z - bj.z); g[s][3] = fabsf(bi.w - bj.w);
    }
    float acc[4] = {0.f, 0.f, 0.f, 0.f};
    int ali = tid & 15, alh = (tid >> 4) * 4;     // tid<128: one float4 along h
    int blj = tid & 63, blh = (tid >> 6) * 8;     // 2 float4 along h
    for (int c4 = 0; c4 < 2; ++c4) {
        int hb = (z * 2 + c4) * 32;
        if (tid < 128) {
            int base = (i0 + ali) * 512 + hb + alh;
            float4 a4 = *(const float4*)(b1f + hb + alh);
#pragma unroll
            for (int p = 0; p < 8; ++p) {
                float4 v = *(const float4*)(pp + p * 262144 + base);
                a4.x += v.x; a4.y += v.y; a4.z += v.z; a4.w += v.w;
            }
            As1[(alh + 0) * 17 + ali] = a4.x;
            As1[(alh + 1) * 17 + ali] = a4.y;
            As1[(alh + 2) * 17 + ali] = a4.z;
            As1[(alh + 3) * 17 + ali] = a4.w;
        }
#pragma unroll
        for (int s = 0; s < 2; ++s) {
            int h = blh + 4 * s;
            int base = (j0 + blj) * 512 + 256 + hb + h;
            float4 u4 = make_float4(0.f, 0.f, 0.f, 0.f);
#pragma unroll
            for (int p = 0; p < 8; ++p) {
                float4 v = *(const float4*)(pp + p * 262144 + base);
                u4.x += v.x; u4.y += v.y; u4.z += v.z; u4.w += v.w;
            }
            Bs[(h + 0) * 64 + blj] = u4.x;
            Bs[(h + 1) * 64 + blj] = u4.y;
            Bs[(h + 2) * 64 + blj] = u4.z;
            Bs[(h + 3) * 64 + blj] = u4.w;
        }
        if (tid < 32) {
            int hg = hb + tid;
            *(float4*)(Awg + tid * 4) = *(const float4*)(w1f + hg * W1_LD + 2048);
            Aw2[tid] = w2f[hg];
        }
        __syncthreads();
#pragma unroll
        for (int hh = 0; hh < 32; ++hh) {
            float4 wg = *(const float4*)(Awg + hh * 4);
            float w2v = Aw2[hh];
            float p2v = Bs[hh * 64 + tx];
            float s0 = As1[hh * 17 + ty * 4 + 0];
            float s1 = As1[hh * 17 + ty * 4 + 1];
            float s2 = As1[hh * 17 + ty * 4 + 2];
            float s3 = As1[hh * 17 + ty * 4 + 3];
            float t0 = s0 + p2v;
            t0 = fmaf(g[0][0], wg.x, t0); t0 = fmaf(g[0][1], wg.y, t0);
            t0 = fmaf(g[0][2], wg.z, t0); t0 = fmaf(g[0][3], wg.w, t0);
            acc[0] = fmaf(w2v, fmaxf(t0, 0.f), acc[0]);
            float t1 = s1 + p2v;
            t1 = fmaf(g[1][0], wg.x, t1); t1 = fmaf(g[1][1], wg.y, t1);
            t1 = fmaf(g[1][2], wg.z, t1); t1 = fmaf(g[1][3], wg.w, t1);
            acc[1] = fmaf(w2v, fmaxf(t1, 0.f), acc[1]);
            float t2 = s2 + p2v;
            t2 = fmaf(g[2][0], wg.x, t2); t2 = fmaf(g[2][1], wg.y, t2);
            t2 = fmaf(g[2][2], wg.z, t2); t2 = fmaf(g[2][3], wg.w, t2);
            acc[2] = fmaf(w2v, fmaxf(t2, 0.f), acc[2]);
            float t3 = s3 + p2v;
            t3 = fmaf(g[3][0], wg.x, t3); t3 = fmaf(g[3][1], wg.y, t3);
            t3 = fmaf(g[3][2], wg.z, t3); t3 = fmaf(g[3][3], wg.w, t3);
            acc[3] = fmaf(w2v, fmaxf(t3, 0.f), acc[3]);
        }
        __syncthreads();
    }
    float* po = (z == 0) ? r0 : (prel + (z - 1) * 262144);
#pragma unroll
    for (int s = 0; s < 4; ++s)
        po[(i0 + ty * 4 + s) * 512 + j0 + tx] = acc[s];
}

// ---------- K3: sum 4 rel partials + b2 -> rel_out; per-row top-(k+1); in-degrees ----------
__global__ void k_topk(const float* __restrict__ r0, const float* __restrict__ prel,
                       const float* __restrict__ b2f, const int* __restrict__ kp,
                       int* __restrict__ nbrs, int* __restrict__ count,
                       float* __restrict__ rel_out) {
    int i = blockIdx.x, lane = threadIdx.x;
    int k = *kp;
    float b2v = b2f[0];
    float v[8]; int ids[8];
    for (int q = 0; q < 8; ++q) {
        int j = lane + 64 * q;
        float val = r0[i * 512 + j] + prel[i * 512 + j]
                  + prel[262144 + i * 512 + j] + prel[524288 + i * 512 + j] + b2v;
        rel_out[i * 512 + j] = val;   // same thread reads then writes this slot
        v[q] = val;
        ids[q] = j;
    }
    for (int pick = 0; pick < k + 1; ++pick) {
        float bv = -INFINITY; int bidx = 1 << 30;
        for (int q = 0; q < 8; ++q)
            if (v[q] > bv || (v[q] == bv && ids[q] < bidx)) { bv = v[q]; bidx = ids[q]; }
        for (int off = 32; off > 0; off >>= 1) {
            float ov = __shfl_down(bv, off);
            int oi = __shfl_down(bidx, off);
            if (ov > bv || (ov == bv && oi < bidx)) { bv = ov; bidx = oi; }
        }
        bv = __shfl(bv, 0); bidx = __shfl(bidx, 0);
        if (pick >= 1 && lane == 0) {
            nbrs[i * 8 + (pick - 1)] = bidx;
            atomicAdd(&count[bidx], 1);
        }
        for (int q = 0; q < 8; ++q) if (ids[q] == bidx) v[q] = -INFINITY;
    }
    if (lane == 0) atomicAdd(&count[i], 1);
}

// ---------- K4: exclusive scan + fill in-edge lists (fused, 1 block, LDS cursor) ----------
__global__ void k_scanfill(const int* __restrict__ count, const int* __restrict__ nbrs,
                           const int* __restrict__ kp,
                           int* __restrict__ offs, int* __restrict__ inlist) {
    __shared__ int s[512];
    __shared__ int excl[512];
    __shared__ int cur[512];
    int t = threadIdx.x;
    int c = count[t];
    s[t] = c; cur[t] = 0;
    __syncthreads();
    for (int off = 1; off < 512; off <<= 1) {
        int v = (t >= off) ? s[t - off] : 0;
        __syncthreads();
        s[t] += v;
        __syncthreads();
    }
    offs[t + 1] = s[t];
    if (t == 0) offs[0] = 0;
    excl[t] = s[t] - c;
    __syncthreads();
    int k = *kp;
    for (int q = 0; q < k; ++q) {
        int d = nbrs[t * 8 + q] & 511;
        int pos = atomicAdd(&cur[d], 1);
        inlist[excl[d] + pos] = t;
    }
    int pos = atomicAdd(&cur[t], 1);
    inlist[excl[t] + pos] = t;
}

// ---------- K6a: split feats + gat1_w (K rows 0..1023) into bf16 hi/lo MFMA-fragment
// layout arrays. A-frag: (it,kt,lane,e) = feats[it*16+(lane&15)][kt*32+(lane>>4)*8+e].
// B-frag: (kt,nt,lane,e) = Wg[kt*32+(lane>>4)*8+e][nt*16+(lane&15)].
// Blocks 0..1 also zero count (replaces memset dispatch).
__global__ __launch_bounds__(256) void k_conv(const float* __restrict__ feats,
                                              const float* __restrict__ Wg,
                                              ushort* __restrict__ Afh,
                                              ushort* __restrict__ Afl,
                                              ushort* __restrict__ Bfh,
                                              ushort* __restrict__ Bfl,
                                              int* __restrict__ zero_ints) {
    int b = blockIdx.x, t = threadIdx.x;
    if (b < 2) zero_ints[b * 256 + t] = 0;
    int lane = t & 63;
    float x[8];
    size_t off;
    if (b < 256) {   // A: 256 blocks x 256 thr = 65536 = 32 it x 32 kt x 64 lanes
        int g = b * 256 + t;
        int q = g >> 6;
        int it = q & 31, kt = q >> 5;
        int row = it * 16 + (lane & 15);
        int col0 = kt * 32 + (lane >> 4) * 8;
        const float* src = feats + row * 1024 + col0;
        float4 u0 = *(const float4*)(src);
        float4 u1 = *(const float4*)(src + 4);
        x[0] = u0.x; x[1] = u0.y; x[2] = u0.z; x[3] = u0.w;
        x[4] = u1.x; x[5] = u1.y; x[6] = u1.z; x[7] = u1.w;
        off = ((size_t)(kt * 32 + it) * 64 + lane) * 8;
    } else {          // B: 512 blocks = 32 kt x 64 nt x 64 lanes
        int g = (b - 256) * 256 + t;
        int q = g >> 6;
        int nt = q & 63, kt = q >> 6;
        int col = nt * 16 + (lane & 15);
        int row0 = kt * 32 + (lane >> 4) * 8;
#pragma unroll
        for (int e = 0; e < 8; ++e) x[e] = Wg[(row0 + e) * 1024 + col];
        off = ((size_t)(kt * 64 + nt) * 64 + lane) * 8;
        Afh = Bfh; Afl = Bfl;   // redirect output
    }
    uint uh[4], ul[4];
#pragma unroll
    for (int p = 0; p < 4; ++p) {
        ushort h0 = bf16_rne(x[2 * p]);
        ushort h1 = bf16_rne(x[2 * p + 1]);
        float f0 = __uint_as_float((unsigned)h0 << 16);
        float f1 = __uint_as_float((unsigned)h1 << 16);
        ushort l0 = bf16_rne(x[2 * p] - f0);
        ushort l1 = bf16_rne(x[2 * p + 1] - f1);
        uh[p] = (uint)h0 | ((uint)h1 << 16);
        ul[p] = (uint)l0 | ((uint)l1 << 16);
    }
    *(uint4*)(Afh + off) = make_uint4(uh[0], uh[1], uh[2], uh[3]);
    *(uint4*)(Afl + off) = make_uint4(ul[0], ul[1], ul[2], ul[3]);
}

// ---------- K6b: GAT1 GEMM via bf16 MFMA, 2-term split (hh + hl + lh) ----------
// grid (16 n, 8 i, 4 z), 256 thr = 4 waves, each wave 32x32 out, block 64x64.
// z-split K: block handles kt = z*8 .. z*8+7 -> partial P[z]. 512 blocks, 2/CU.
__global__ __launch_bounds__(256) void k_mm1(const ushort* __restrict__ Afh,
                                             const ushort* __restrict__ Afl,
                                             const ushort* __restrict__ Bfh,
                                             const ushort* __restrict__ Bfl,
                                             float* __restrict__ P) {
    int nt0 = blockIdx.x * 4, it0 = blockIdx.y * 4, z = blockIdx.z;
    int t = threadIdx.x, lane = t & 63, w = t >> 6;
    int wr = w >> 1, wc = w & 1, sub = w;
    __shared__ uint4 buf[2][4][4][64];   // [dbuf][Ah Al Bh Bl][sub][lane]
    const uint4* gAh = (const uint4*)Afh;
    const uint4* gAl = (const uint4*)Afl;
    const uint4* gBh = (const uint4*)Bfh;
    const uint4* gBl = (const uint4*)Bfl;
    f32x4 acc[2][2];
    f32x4 zero = {0.f, 0.f, 0.f, 0.f};
    acc[0][0] = zero; acc[0][1] = zero; acc[1][0] = zero; acc[1][1] = zero;
    int ktg = z * 8;
    uint4 rah = gAh[(ktg * 32 + it0 + sub) * 64 + lane];
    uint4 ral = gAl[(ktg * 32 + it0 + sub) * 64 + lane];
    uint4 rbh = gBh[(ktg * 64 + nt0 + sub) * 64 + lane];
    uint4 rbl = gBl[(ktg * 64 + nt0 + sub) * 64 + lane];
    for (int kk = 0; kk < 8; ++kk) {
        int cur = kk & 1;
        buf[cur][0][sub][lane] = rah;
        buf[cur][1][sub][lane] = ral;
        buf[cur][2][sub][lane] = rbh;
        buf[cur][3][sub][lane] = rbl;
        __syncthreads();
        if (kk < 7) {
            int kn = ktg + kk + 1;
            rah = gAh[(kn * 32 + it0 + sub) * 64 + lane];
            ral = gAl[(kn * 32 + it0 + sub) * 64 + lane];
            rbh = gBh[(kn * 64 + nt0 + sub) * 64 + lane];
            rbl = gBl[(kn * 64 + nt0 + sub) * 64 + lane];
        }
        short8 ah[2], al[2], bh[2], bl[2];
#pragma unroll
        for (int i = 0; i < 2; ++i) {
            ah[i] = *(const short8*)&buf[cur][0][2 * wr + i][lane];
            al[i] = *(const short8*)&buf[cur][1][2 * wr + i][lane];
            bh[i] = *(const short8*)&buf[cur][2][2 * wc + i][lane];
            bl[i] = *(const short8*)&buf[cur][3][2 * wc + i][lane];
        }
#pragma unroll
        for (int i = 0; i < 2; ++i)
#pragma unroll
            for (int j = 0; j < 2; ++j) {
                acc[i][j] = __builtin_amdgcn_mfma_f32_16x16x32_bf16(ah[i], bh[j], acc[i][j], 0, 0, 0);
                acc[i][j] = __builtin_amdgcn_mfma_f32_16x16x32_bf16(ah[i], bl[j], acc[i][j], 0, 0, 0);
                acc[i][j] = __builtin_amdgcn_mfma_f32_16x16x32_bf16(al[i], bh[j], acc[i][j], 0, 0, 0);
            }
        __syncthreads();
    }
    float* outp = P + z * 524288;
#pragma unroll
    for (int i = 0; i < 2; ++i)
#pragma unroll
        for (int j = 0; j < 2; ++j) {
            int rbase = (it0 + 2 * wr + i) * 16 + (lane >> 4) * 4;
            int c = (nt0 + 2 * wc + j) * 16 + (lane & 15);
#pragma unroll
            for (int r = 0; r < 4; ++r)
                outp[(size_t)(rbase + r) * 1024 + c] = acc[i][j][r];
        }
}

// ---------- K7: GAT1 epilogue: sum 4 partials + geom rows + a_s1/a_d1 ----------
__global__ __launch_bounds__(256) void k_gat1ep(const float* __restrict__ P,
                                                const float* __restrict__ boxesf,
                                                const float* __restrict__ Wg,
                                                const float* __restrict__ asrcf,
                                                const float* __restrict__ adstf,
                                                float* __restrict__ hX,
                                                float* __restrict__ a_s1,
                                                float* __restrict__ a_d1) {
    int i = blockIdx.x, t = threadIdx.x;
    const float* P0 = P;
    const float* P1 = P + 524288;
    const float* P2 = P + 1048576;
    const float* P3 = P + 1572864;
    float4 bx = *(const float4*)(boxesf + i * 4);
    float g0 = bx.x / 800.f, g1 = bx.y / 800.f;
    float g2 = bx.z / 800.f - g0, g3 = bx.w / 800.f - g1;
    float ps[4], pd[4];
#pragma unroll
    for (int q = 0; q < 4; ++q) {
        int c = q * 256 + t;
        float v = P0[i * 1024 + c] + P1[i * 1024 + c] + P2[i * 1024 + c] + P3[i * 1024 + c];
        v = fmaf(g0, Wg[1024 * 1024 + c], v);
        v = fmaf(g1, Wg[1025 * 1024 + c], v);
        v = fmaf(g2, Wg[1026 * 1024 + c], v);
        v = fmaf(g3, Wg[1027 * 1024 + c], v);
        hX[i * 1024 + c] = v;          // in-place over P0 row i (same thread RAW only)
        ps[q] = v * asrcf[c];
        pd[q] = v * adstf[c];
    }
    __shared__ float rs[4][4], rd[4][4];
    int wid = t >> 6;
#pragma unroll
    for (int off = 32; off > 0; off >>= 1) {
#pragma unroll
        for (int q = 0; q < 4; ++q) {
            ps[q] += __shfl_down(ps[q], off);
            pd[q] += __shfl_down(pd[q], off);
        }
    }
    if ((t & 63) == 0) {
#pragma unroll
        for (int q = 0; q < 4; ++q) { rs[wid][q] = ps[q]; rd[wid][q] = pd[q]; }
    }
    __syncthreads();
    if (t < 4)
        a_s1[i * 4 + t] = rs[0][t] + rs[1][t] + rs[2][t] + rs[3][t];
    else if (t < 8) {
        int q = t - 4;
        a_d1[i * 4 + q] = rd[0][q] + rd[1][q] + rd[2][q] + rd[3][q];
    }
}

// ---------- K8: GAT1 per-dst softmax + aggregate + bias + relu ----------
__global__ void k_aggr1(const float* __restrict__ hX,
                        const float* __restrict__ a_s, const float* __restrict__ a_d,
                        const int* __restrict__ offs, const int* __restrict__ inlist,
                        const float* __restrict__ bias,
                        float* __restrict__ h1) {
    int n = blockIdx.x, t = threadIdx.x;
    int beg = offs[n], deg = offs[n + 1] - beg;
    if (deg > 513) deg = 513;
    __shared__ int srcs[520];
    __shared__ float alpha[520][4];
    __shared__ float sm[4];
    for (int e = t; e < deg; e += 256) srcs[e] = inlist[beg + e] & 511;
    __syncthreads();
    for (int idx = t; idx < deg * 4; idx += 256) {
        int e = idx >> 2, q = idx & 3;
        float sc = a_s[srcs[e] * 4 + q] + a_d[n * 4 + q];
        alpha[e][q] = (sc >= 0.f) ? sc : 0.2f * sc;
    }
    __syncthreads();
    if (t < 4) {
        float m = -INFINITY;
        for (int e = 0; e < deg; ++e) m = fmaxf(m, alpha[e][t]);
        if (!isfinite(m)) m = 0.f;
        float s = 0.f;
        for (int e = 0; e < deg; ++e) { float ex = expf(alpha[e][t] - m); alpha[e][t] = ex; s += ex; }
        sm[t] = s + 1e-16f;
    }
    __syncthreads();
    for (int idx = t; idx < deg * 4; idx += 256) {
        int e = idx >> 2, q = idx & 3;
        alpha[e][q] /= sm[q];
    }
    __syncthreads();
    for (int q = 0; q < 4; ++q) {
        float acc = 0.f;
        for (int e = 0; e < deg; ++e) acc += alpha[e][q] * hX[srcs[e] * 1024 + q * 256 + t];
        h1[n * 1024 + q * 256 + t] = fmaxf(acc + bias[q * 256 + t], 0.f);
    }
}

// ---------- K9: GAT2 GEMM + a_s2/a_d2 (2-way K-split, 4 accums) ----------
__global__ __launch_bounds__(256) void k_gat2(const float* __restrict__ h1,
                                              const float* __restrict__ Wf,
                                              const float* __restrict__ asrcf,
                                              const float* __restrict__ adstf,
                                              float* __restrict__ h2,
                                              float* __restrict__ a_s2,
                                              float* __restrict__ a_d2) {
    int n = blockIdx.x, t = threadIdx.x;
    __shared__ float xs[1024];
    __shared__ float hbuf[NCLS];
    __shared__ float sred[256], dred[256];
    for (int c = t; c < 1024; c += 256) xs[c] = h1[n * 1024 + c];
    __syncthreads();
    int cls = t & 127, kh = t >> 7;
    float acc = 0.f;
    if (cls < NCLS) {
        const float* wp = Wf + (kh * 512) * NCLS + cls;
        const float* xp = xs + kh * 512;
        float a0 = 0.f, a1 = 0.f, a2 = 0.f, a3 = 0.f;
        for (int c = 0; c < 512; c += 4) {
            a0 = fmaf(xp[c + 0], wp[(c + 0) * NCLS], a0);
            a1 = fmaf(xp[c + 1], wp[(c + 1) * NCLS], a1);
            a2 = fmaf(xp[c + 2], wp[(c + 2) * NCLS], a2);
            a3 = fmaf(xp[c + 3], wp[(c + 3) * NCLS], a3);
        }
        acc = (a0 + a1) + (a2 + a3);
    }
    if (kh == 0 && cls < NCLS) hbuf[cls] = acc;
    __syncthreads();
    float tot = 0.f;
    int act = (kh == 1 && cls < NCLS);
    if (act) { tot = acc + hbuf[cls]; h2[n * NCLS + cls] = tot; }
    sred[t] = act ? tot * asrcf[cls] : 0.f;
    dred[t] = act ? tot * adstf[cls] : 0.f;
    __syncthreads();
    for (int s = 128; s > 0; s >>= 1) {
        if (t < s) { sred[t] += sred[t + s]; dred[t] += dred[t + s]; }
        __syncthreads();
    }
    if (t == 0) { a_s2[n] = sred[0]; a_d2[n] = dred[0]; }
}

// ---------- K10: GAT2 aggregate -> logits + softmax probs ----------
__global__ void k_aggr2(const float* __restrict__ h2,
                        const float* __restrict__ a_s2, const float* __restrict__ a_d2,
                        const int* __restrict__ offs, const int* __restrict__ inlist,
                        const float* __restrict__ bias,
                        float* __restrict__ logits_out,
                        float* __restrict__ probs_out) {
    int n = blockIdx.x, t = threadIdx.x;
    int beg = offs[n], deg = offs[n + 1] - beg;
    if (deg > 513) deg = 513;
    __shared__ int srcs[520];
    __shared__ float alpha[520];
    __shared__ float red[128];
    __shared__ float smden;
    for (int e = t; e < deg; e += 128) {
        int s = inlist[beg + e] & 511;
        srcs[e] = s;
        float sc = a_s2[s] + a_d2[n];
        alpha[e] = (sc >= 0.f) ? sc : 0.2f * sc;
    }
    __syncthreads();
    if (t == 0) {
        float m = -INFINITY;
        for (int e = 0; e < deg; ++e) m = fmaxf(m, alpha[e]);
        if (!isfinite(m)) m = 0.f;
        float s = 0.f;
        for (int e = 0; e < deg; ++e) { float ex = expf(alpha[e] - m); alpha[e] = ex; s += ex; }
        smden = s + 1e-16f;
    }
    __syncthreads();
    float logit = 0.f;
    if (t < NCLS) {
        float acc = 0.f;
        for (int e = 0; e < deg; ++e) acc += alpha[e] * h2[srcs[e] * NCLS + t];
        logit = acc / smden + bias[t];
        logits_out[n * NCLS + t] = logit;
    }
    red[t] = (t < NCLS) ? logit : -INFINITY; __syncthreads();
    for (int s = 64; s > 0; s >>= 1) { if (t < s) red[t] = fmaxf(red[t], red[t + s]); __syncthreads(); }
    float mx = red[0];
    __syncthreads();
    float ex = (t < NCLS) ? expf(logit - mx) : 0.f;
    red[t] = ex; __syncthreads();
    for (int s = 64; s > 0; s >>= 1) { if (t < s) red[t] += red[t + s]; __syncthreads(); }
    float inv = 1.f / red[0];
    if (t < NCLS) probs_out[n * NCLS + t] = ex * inv;
}

// ---------- launch ----------
extern "C" void kernel_launch(void* const* d_in, const int* in_sizes, int n_in,
                              void* d_out, int out_size, void* d_ws, size_t ws_size,
                              hipStream_t stream) {
    const float* feats   = (const float*)d_in[0];
    const float* boxes   = (const float*)d_in[1];
    const float* repn_w1 = (const float*)d_in[2];
    const float* repn_b1 = (const float*)d_in[3];
    const float* repn_w2 = (const float*)d_in[4];
    const float* repn_b2 = (const float*)d_in[5];
    const float* gat1_w    = (const float*)d_in[6];
    const float* gat1_asrc = (const float*)d_in[7];
    const float* gat1_adst = (const float*)d_in[8];
    const float* gat1_b    = (const float*)d_in[9];
    const float* gat2_w    = (const float*)d_in[10];
    const float* gat2_asrc = (const float*)d_in[11];
    const float* gat2_adst = (const float*)d_in[12];
    const float* gat2_b    = (const float*)d_in[13];
    const int* kp = (const int*)d_in[14];

    float* out = (float*)d_out;
    float* logits_out = out;
    float* probs_out  = out + 512 * NCLS;
    float* rel_out    = out + 2 * 512 * NCLS;

    // Workspace map (floats):
    //  [0,2097152)        pp: 8 x 512x512 p12 partials (p12 -> rel); then
    //                     P: 4 x 512x1024 gat1 MFMA partials aliased here (mm1 -> gat1ep);
    //                     hX aliases P0 (gat1ep -> aggr1); h1 aliases P1 (aggr1 -> gat2)
    //  [2097152,2883584)  prel: 3 rel partials (z=1..3), live rel -> topk
    //  [2883584,4456448)  bf16 frag arrays: Afh, Afl (262144 floats each),
    //                     Bfh, Bfl (524288 floats each)
    //  [4456448, ...)     h2 / a_s2 / a_d2 / a_s1 / a_d1 / int block
    float* wsf   = (float*)d_ws;
    float* pp    = wsf;
    float* P     = wsf;                 // alias pp (mm1 launches after k_rel)
    float* hX    = P;
    float* h1    = P + 524288;
    float* prel  = wsf + 2097152;
    ushort* Afh  = (ushort*)(wsf + 2883584);
    ushort* Afl  = (ushort*)(wsf + 3145728);
    ushort* Bfh  = (ushort*)(wsf + 3407872);
    ushort* Bfl  = (ushort*)(wsf + 3932160);
    float* h2    = wsf + 4456448;       // 46592, pad to 47104
    float* a_s2  = wsf + 4503552;
    float* a_d2  = wsf + 4504064;
    float* a_s1  = wsf + 4504576;
    float* a_d1  = wsf + 4506624;
    int* ib      = (int*)(wsf + 4508672);
    int* count   = ib;                  // 512 (zeroed by k_conv)
    int* nbrs    = ib + 1024;           // 4096
    int* offs    = ib + 5120;           // 520
    int* inlist  = ib + 5640;           // 4096

    k_conv<<<dim3(768), dim3(256), 0, stream>>>(feats, gat1_w, Afh, Afl, Bfh, Bfl, ib);
    k_p12<<<dim3(8, 16, 8), dim3(128), 0, stream>>>(feats, repn_w1, pp);
    k_rel<<<dim3(8, 32, 4), dim3(256), 0, stream>>>(pp, repn_w1, repn_b1, repn_w2,
                                                    boxes, rel_out, prel);
    k_topk<<<dim3(512), dim3(64), 0, stream>>>(rel_out, prel, repn_b2, kp,
                                               nbrs, count, rel_out);
    k_scanfill<<<dim3(1), dim3(512), 0, stream>>>(count, nbrs, kp, offs, inlist);
    k_mm1<<<dim3(16, 8, 4), dim3(256), 0, stream>>>(Afh, Afl, Bfh, Bfl, P);
    k_gat1ep<<<dim3(512), dim3(256), 0, stream>>>(P, boxes, gat1_w, gat1_asrc,
                                                  gat1_adst, hX, a_s1, a_d1);
    k_aggr1<<<dim3(512), dim3(256), 0, stream>>>(hX, a_s1, a_d1, offs, inlist, gat1_b, h1);
    k_gat2<<<dim3(512), dim3(256), 0, stream>>>(h1, gat2_w, gat2_asrc, gat2_adst,
                                                h2, a_s2, a_d2);
    k_aggr2<<<dim3(512), dim3(128), 0, stream>>>(h2, a_s2, a_d2, offs, inlist, gat2_b,
                                                 logits_out, probs_out);
}

// Round 5
// 185.967 us; speedup vs baseline: 1.0975x; 1.0975x over previous
//
#include <hip/hip_runtime.h>

// Inputs and outputs are float32 (established R1/R3).
#define NCLS 91
#define W1_LD 2052   // repn_w1 row length (2C+4)

typedef __attribute__((ext_vector_type(8))) short short8;   // 8 bf16 (4 VGPRs)
typedef __attribute__((ext_vector_type(4))) float f32x4;    // MFMA C/D

__device__ inline ushort bf16_rne(float x) {
    unsigned u = __float_as_uint(x);
    return (ushort)((u + 0x7fffu + ((u >> 16) & 1u)) >> 16);
}

// ---------- K1: p_part[z][i][r] = feats[i, z*128:+128] . Wcomb[r, z*128:+128] ----------
// Wcomb rows 0..255 = wf1, 256..511 = wf2. grid (8 r-tiles, 16 i-tiles, 8 z), 128 thr.
// z=8 K-split: 1024 blocks -> 4 blocks/CU, 8 waves/CU in 4 independent barrier groups.
__global__ __launch_bounds__(128) void k_p12(const float* __restrict__ feats,
                                             const float* __restrict__ w1f,
                                             float* __restrict__ pp) {
    int r0 = blockIdx.x * 64, i0 = blockIdx.y * 32, z = blockIdx.z;
    int tid = threadIdx.x, tx = tid & 15, ty = tid >> 4;
    __shared__ float As[64 * 32];   // [k][i]
    __shared__ float Bs[64 * 64];   // [k][r]
    float* pout = pp + z * 262144;
    int ai = tid & 31, akq = (tid >> 5) * 16;          // A loader: 4 float4 along k
    int br = tid & 63, bkq = (tid >> 6) * 32;          // B loader: 8 float4 along k
    const float* abase = feats + (i0 + ai) * 1024 + z * 128 + akq;
    int rg = r0 + br;
    const float* bbase = w1f + (rg < 256 ? rg * W1_LD : (rg - 256) * W1_LD + 1024)
                       + z * 128 + bkq;
    float4 av[4], bv[8];
#pragma unroll
    for (int s = 0; s < 4; ++s) av[s] = *(const float4*)(abase + 4 * s);
#pragma unroll
    for (int s = 0; s < 8; ++s) bv[s] = *(const float4*)(bbase + 4 * s);
    float acc[4][4] = {};
    for (int kt = 0; kt < 2; ++kt) {
#pragma unroll
        for (int s = 0; s < 4; ++s) {   // transpose store: lanes distinct ai -> 2-way max
            int k = akq + 4 * s;
            As[(k + 0) * 32 + ai] = av[s].x; As[(k + 1) * 32 + ai] = av[s].y;
            As[(k + 2) * 32 + ai] = av[s].z; As[(k + 3) * 32 + ai] = av[s].w;
        }
#pragma unroll
        for (int s = 0; s < 8; ++s) {   // transpose store: lanes distinct br -> 2-way max
            int k = bkq + 4 * s;
            Bs[(k + 0) * 64 + br] = bv[s].x; Bs[(k + 1) * 64 + br] = bv[s].y;
            Bs[(k + 2) * 64 + br] = bv[s].z; Bs[(k + 3) * 64 + br] = bv[s].w;
        }
        __syncthreads();
        if (kt + 1 < 2) {
#pragma unroll
            for (int s = 0; s < 4; ++s) av[s] = *(const float4*)(abase + 64 + 4 * s);
#pragma unroll
            for (int s = 0; s < 8; ++s) bv[s] = *(const float4*)(bbase + 64 + 4 * s);
        }
#pragma unroll
        for (int k = 0; k < 64; ++k) {
            float4 a4 = *(const float4*)(As + k * 32 + ty * 4);
            float4 b4 = *(const float4*)(Bs + k * 64 + tx * 4);
            acc[0][0] = fmaf(a4.x, b4.x, acc[0][0]); acc[0][1] = fmaf(a4.x, b4.y, acc[0][1]);
            acc[0][2] = fmaf(a4.x, b4.z, acc[0][2]); acc[0][3] = fmaf(a4.x, b4.w, acc[0][3]);
            acc[1][0] = fmaf(a4.y, b4.x, acc[1][0]); acc[1][1] = fmaf(a4.y, b4.y, acc[1][1]);
            acc[1][2] = fmaf(a4.y, b4.z, acc[1][2]); acc[1][3] = fmaf(a4.y, b4.w, acc[1][3]);
            acc[2][0] = fmaf(a4.z, b4.x, acc[2][0]); acc[2][1] = fmaf(a4.z, b4.y, acc[2][1]);
            acc[2][2] = fmaf(a4.z, b4.z, acc[2][2]); acc[2][3] = fmaf(a4.z, b4.w, acc[2][3]);
            acc[3][0] = fmaf(a4.w, b4.x, acc[3][0]); acc[3][1] = fmaf(a4.w, b4.y, acc[3][1]);
            acc[3][2] = fmaf(a4.w, b4.z, acc[3][2]); acc[3][3] = fmaf(a4.w, b4.w, acc[3][3]);
        }
        __syncthreads();
    }
#pragma unroll
    for (int ii = 0; ii < 4; ++ii)
        *(float4*)(pout + (i0 + ty * 4 + ii) * 512 + r0 + tx * 4) =
            make_float4(acc[ii][0], acc[ii][1], acc[ii][2], acc[ii][3]);
}

// ---------- K1b: collapse 8 pp partials -> ppsum (pure streaming, 9 MB) ----------
__global__ __launch_bounds__(256) void k_psum(const float* __restrict__ pp,
                                              float* __restrict__ ppsum) {
    int idx = (blockIdx.x * 256 + threadIdx.x) * 4;
    float4 a = *(const float4*)(pp + idx);
#pragma unroll
    for (int p = 1; p < 8; ++p) {
        float4 v = *(const float4*)(pp + p * 262144 + idx);
        a.x += v.x; a.y += v.y; a.z += v.z; a.w += v.w;
    }
    *(float4*)(ppsum + idx) = a;
}

// ---------- K2: rel partials, h-chunk split 4-way across z, single-ppsum staging ----------
// grid (8 j, 32 i, 4 z), 256 thr -> 1024 blocks, 4 blocks/CU, 16 waves/CU.
// z handles ch = z*2 .. z*2+1 (h rows z*64..+64). ppsum is L2-resident (1 MB).
// z=0 partial -> r0 (rel_out scratch), z>0 -> prel[z-1]. Final sum + b2 in k_topk.
__global__ __launch_bounds__(256) void k_rel(const float* __restrict__ ppsum,
                                             const float* __restrict__ w1f,
                                             const float* __restrict__ b1f,
                                             const float* __restrict__ w2f,
                                             const float* __restrict__ boxesf,
                                             float* __restrict__ r0,
                                             float* __restrict__ prel) {
    int j0 = blockIdx.x * 64, i0 = blockIdx.y * 16, z = blockIdx.z;
    int tid = threadIdx.x, tx = tid & 63, ty = tid >> 6;
    __shared__ float As1[32 * 17];  // [h][i] pad 17
    __shared__ float Bs[32 * 64];   // [h][j]
    __shared__ float Awg[32 * 4];
    __shared__ float Aw2[32];
    float4 bj = *(const float4*)(boxesf + (j0 + tx) * 4);
    float g[4][4];
#pragma unroll
    for (int s = 0; s < 4; ++s) {
        float4 bi = *(const float4*)(boxesf + (i0 + ty * 4 + s) * 4);
        g[s][0] = fabsf(bi.x - bj.x); g[s][1] = fabsf(bi.y - bj.y);
        g[s][2] = fabsf(bi.z - bj.z); g[s][3] = fabsf(bi.w - bj.w);
    }
    float acc[4] = {0.f, 0.f, 0.f, 0.f};
    int ali = tid & 15, alh = (tid >> 4) * 4;     // tid<128: one float4 along h
    int blj = tid & 63, blh = (tid >> 6) * 8;     // 2 float4 along h
    for (int c4 = 0; c4 < 2; ++c4) {
        int hb = (z * 2 + c4) * 32;
        if (tid < 128) {
            float4 a4 = *(const float4*)(ppsum + (i0 + ali) * 512 + hb + alh);
            float4 b  = *(const float4*)(b1f + hb + alh);
            As1[(alh + 0) * 17 + ali] = a4.x + b.x;
            As1[(alh + 1) * 17 + ali] = a4.y + b.y;
            As1[(alh + 2) * 17 + ali] = a4.z + b.z;
            As1[(alh + 3) * 17 + ali] = a4.w + b.w;
        }
#pragma unroll
        for (int s = 0; s < 2; ++s) {
            int h = blh + 4 * s;
            float4 u4 = *(const float4*)(ppsum + (j0 + blj) * 512 + 256 + hb + h);
            Bs[(h + 0) * 64 + blj] = u4.x;
            Bs[(h + 1) * 64 + blj] = u4.y;
            Bs[(h + 2) * 64 + blj] = u4.z;
            Bs[(h + 3) * 64 + blj] = u4.w;
        }
        if (tid < 32) {
            int hg = hb + tid;
            *(float4*)(Awg + tid * 4) = *(const float4*)(w1f + hg * W1_LD + 2048);
            Aw2[tid] = w2f[hg];
        }
        __syncthreads();
#pragma unroll
        for (int hh = 0; hh < 32; ++hh) {
            float4 wg = *(const float4*)(Awg + hh * 4);
            float w2v = Aw2[hh];
            float p2v = Bs[hh * 64 + tx];
            float s0 = As1[hh * 17 + ty * 4 + 0];
            float s1 = As1[hh * 17 + ty * 4 + 1];
            float s2 = As1[hh * 17 + ty * 4 + 2];
            float s3 = As1[hh * 17 + ty * 4 + 3];
            float t0 = s0 + p2v;
            t0 = fmaf(g[0][0], wg.x, t0); t0 = fmaf(g[0][1], wg.y, t0);
            t0 = fmaf(g[0][2], wg.z, t0); t0 = fmaf(g[0][3], wg.w, t0);
            acc[0] = fmaf(w2v, fmaxf(t0, 0.f), acc[0]);
            float t1 = s1 + p2v;
            t1 = fmaf(g[1][0], wg.x, t1); t1 = fmaf(g[1][1], wg.y, t1);
            t1 = fmaf(g[1][2], wg.z, t1); t1 = fmaf(g[1][3], wg.w, t1);
            acc[1] = fmaf(w2v, fmaxf(t1, 0.f), acc[1]);
            float t2 = s2 + p2v;
            t2 = fmaf(g[2][0], wg.x, t2); t2 = fmaf(g[2][1], wg.y, t2);
            t2 = fmaf(g[2][2], wg.z, t2); t2 = fmaf(g[2][3], wg.w, t2);
            acc[2] = fmaf(w2v, fmaxf(t2, 0.f), acc[2]);
            float t3 = s3 + p2v;
            t3 = fmaf(g[3][0], wg.x, t3); t3 = fmaf(g[3][1], wg.y, t3);
            t3 = fmaf(g[3][2], wg.z, t3); t3 = fmaf(g[3][3], wg.w, t3);
            acc[3] = fmaf(w2v, fmaxf(t3, 0.f), acc[3]);
        }
        __syncthreads();
    }
    float* po = (z == 0) ? r0 : (prel + (z - 1) * 262144);
#pragma unroll
    for (int s = 0; s < 4; ++s)
        po[(i0 + ty * 4 + s) * 512 + j0 + tx] = acc[s];
}

// ---------- K3: sum 4 rel partials + b2 -> rel_out; per-row top-(k+1); in-degrees ----------
__global__ void k_topk(const float* __restrict__ r0, const float* __restrict__ prel,
                       const float* __restrict__ b2f, const int* __restrict__ kp,
                       int* __restrict__ nbrs, int* __restrict__ count,
                       float* __restrict__ rel_out) {
    int i = blockIdx.x, lane = threadIdx.x;
    int k = *kp;
    float b2v = b2f[0];
    float v[8]; int ids[8];
    for (int q = 0; q < 8; ++q) {
        int j = lane + 64 * q;
        float val = r0[i * 512 + j] + prel[i * 512 + j]
                  + prel[262144 + i * 512 + j] + prel[524288 + i * 512 + j] + b2v;
        rel_out[i * 512 + j] = val;   // same thread reads then writes this slot
        v[q] = val;
        ids[q] = j;
    }
    for (int pick = 0; pick < k + 1; ++pick) {
        float bv = -INFINITY; int bidx = 1 << 30;
        for (int q = 0; q < 8; ++q)
            if (v[q] > bv || (v[q] == bv && ids[q] < bidx)) { bv = v[q]; bidx = ids[q]; }
        for (int off = 32; off > 0; off >>= 1) {
            float ov = __shfl_down(bv, off);
            int oi = __shfl_down(bidx, off);
            if (ov > bv || (ov == bv && oi < bidx)) { bv = ov; bidx = oi; }
        }
        bv = __shfl(bv, 0); bidx = __shfl(bidx, 0);
        if (pick >= 1 && lane == 0) {
            nbrs[i * 8 + (pick - 1)] = bidx;
            atomicAdd(&count[bidx], 1);
        }
        for (int q = 0; q < 8; ++q) if (ids[q] == bidx) v[q] = -INFINITY;
    }
    if (lane == 0) atomicAdd(&count[i], 1);
}

// ---------- K4: exclusive scan + fill in-edge lists (fused, 1 block, LDS cursor) ----------
__global__ void k_scanfill(const int* __restrict__ count, const int* __restrict__ nbrs,
                           const int* __restrict__ kp,
                           int* __restrict__ offs, int* __restrict__ inlist) {
    __shared__ int s[512];
    __shared__ int excl[512];
    __shared__ int cur[512];
    int t = threadIdx.x;
    int c = count[t];
    s[t] = c; cur[t] = 0;
    __syncthreads();
    for (int off = 1; off < 512; off <<= 1) {
        int v = (t >= off) ? s[t - off] : 0;
        __syncthreads();
        s[t] += v;
        __syncthreads();
    }
    offs[t + 1] = s[t];
    if (t == 0) offs[0] = 0;
    excl[t] = s[t] - c;
    __syncthreads();
    int k = *kp;
    for (int q = 0; q < k; ++q) {
        int d = nbrs[t * 8 + q] & 511;
        int pos = atomicAdd(&cur[d], 1);
        inlist[excl[d] + pos] = t;
    }
    int pos = atomicAdd(&cur[t], 1);
    inlist[excl[t] + pos] = t;
}

// ---------- K6a: split feats + gat1_w (K rows 0..1023) into bf16 hi/lo MFMA-fragment
// layout arrays. A-frag: (it,kt,lane,e) = feats[it*16+(lane&15)][kt*32+(lane>>4)*8+e].
// B-frag: (kt,nt,lane,e) = Wg[kt*32+(lane>>4)*8+e][nt*16+(lane&15)].
// Blocks 0..1 also zero count (replaces memset dispatch).
__global__ __launch_bounds__(256) void k_conv(const float* __restrict__ feats,
                                              const float* __restrict__ Wg,
                                              ushort* __restrict__ Afh,
                                              ushort* __restrict__ Afl,
                                              ushort* __restrict__ Bfh,
                                              ushort* __restrict__ Bfl,
                                              int* __restrict__ zero_ints) {
    int b = blockIdx.x, t = threadIdx.x;
    if (b < 2) zero_ints[b * 256 + t] = 0;
    int lane = t & 63;
    float x[8];
    size_t off;
    if (b < 256) {   // A: 256 blocks x 256 thr = 65536 = 32 it x 32 kt x 64 lanes
        int g = b * 256 + t;
        int q = g >> 6;
        int it = q & 31, kt = q >> 5;
        int row = it * 16 + (lane & 15);
        int col0 = kt * 32 + (lane >> 4) * 8;
        const float* src = feats + row * 1024 + col0;
        float4 u0 = *(const float4*)(src);
        float4 u1 = *(const float4*)(src + 4);
        x[0] = u0.x; x[1] = u0.y; x[2] = u0.z; x[3] = u0.w;
        x[4] = u1.x; x[5] = u1.y; x[6] = u1.z; x[7] = u1.w;
        off = ((size_t)(kt * 32 + it) * 64 + lane) * 8;
    } else {          // B: 512 blocks = 32 kt x 64 nt x 64 lanes
        int g = (b - 256) * 256 + t;
        int q = g >> 6;
        int nt = q & 63, kt = q >> 6;
        int col = nt * 16 + (lane & 15);
        int row0 = kt * 32 + (lane >> 4) * 8;
#pragma unroll
        for (int e = 0; e < 8; ++e) x[e] = Wg[(row0 + e) * 1024 + col];
        off = ((size_t)(kt * 64 + nt) * 64 + lane) * 8;
        Afh = Bfh; Afl = Bfl;   // redirect output
    }
    uint uh[4], ul[4];
#pragma unroll
    for (int p = 0; p < 4; ++p) {
        ushort h0 = bf16_rne(x[2 * p]);
        ushort h1 = bf16_rne(x[2 * p + 1]);
        float f0 = __uint_as_float((unsigned)h0 << 16);
        float f1 = __uint_as_float((unsigned)h1 << 16);
        ushort l0 = bf16_rne(x[2 * p] - f0);
        ushort l1 = bf16_rne(x[2 * p + 1] - f1);
        uh[p] = (uint)h0 | ((uint)h1 << 16);
        ul[p] = (uint)l0 | ((uint)l1 << 16);
    }
    *(uint4*)(Afh + off) = make_uint4(uh[0], uh[1], uh[2], uh[3]);
    *(uint4*)(Afl + off) = make_uint4(ul[0], ul[1], ul[2], ul[3]);
}

// ---------- K6b: GAT1 GEMM via bf16 MFMA, 2-term split (hh + hl + lh) ----------
// grid (16 n, 8 i, 4 z), 256 thr = 4 waves, each wave 32x32 out, block 64x64.
// z-split K: block handles kt = z*8 .. z*8+7 -> partial P[z]. 512 blocks, 2/CU.
__global__ __launch_bounds__(256) void k_mm1(const ushort* __restrict__ Afh,
                                             const ushort* __restrict__ Afl,
                                             const ushort* __restrict__ Bfh,
                                             const ushort* __restrict__ Bfl,
                                             float* __restrict__ P) {
    int nt0 = blockIdx.x * 4, it0 = blockIdx.y * 4, z = blockIdx.z;
    int t = threadIdx.x, lane = t & 63, w = t >> 6;
    int wr = w >> 1, wc = w & 1, sub = w;
    __shared__ uint4 buf[2][4][4][64];   // [dbuf][Ah Al Bh Bl][sub][lane]
    const uint4* gAh = (const uint4*)Afh;
    const uint4* gAl = (const uint4*)Afl;
    const uint4* gBh = (const uint4*)Bfh;
    const uint4* gBl = (const uint4*)Bfl;
    f32x4 acc[2][2];
    f32x4 zero = {0.f, 0.f, 0.f, 0.f};
    acc[0][0] = zero; acc[0][1] = zero; acc[1][0] = zero; acc[1][1] = zero;
    int ktg = z * 8;
    uint4 rah = gAh[(ktg * 32 + it0 + sub) * 64 + lane];
    uint4 ral = gAl[(ktg * 32 + it0 + sub) * 64 + lane];
    uint4 rbh = gBh[(ktg * 64 + nt0 + sub) * 64 + lane];
    uint4 rbl = gBl[(ktg * 64 + nt0 + sub) * 64 + lane];
    for (int kk = 0; kk < 8; ++kk) {
        int cur = kk & 1;
        buf[cur][0][sub][lane] = rah;
        buf[cur][1][sub][lane] = ral;
        buf[cur][2][sub][lane] = rbh;
        buf[cur][3][sub][lane] = rbl;
        __syncthreads();
        if (kk < 7) {
            int kn = ktg + kk + 1;
            rah = gAh[(kn * 32 + it0 + sub) * 64 + lane];
            ral = gAl[(kn * 32 + it0 + sub) * 64 + lane];
            rbh = gBh[(kn * 64 + nt0 + sub) * 64 + lane];
            rbl = gBl[(kn * 64 + nt0 + sub) * 64 + lane];
        }
        short8 ah[2], al[2], bh[2], bl[2];
#pragma unroll
        for (int i = 0; i < 2; ++i) {
            ah[i] = *(const short8*)&buf[cur][0][2 * wr + i][lane];
            al[i] = *(const short8*)&buf[cur][1][2 * wr + i][lane];
            bh[i] = *(const short8*)&buf[cur][2][2 * wc + i][lane];
            bl[i] = *(const short8*)&buf[cur][3][2 * wc + i][lane];
        }
#pragma unroll
        for (int i = 0; i < 2; ++i)
#pragma unroll
            for (int j = 0; j < 2; ++j) {
                acc[i][j] = __builtin_amdgcn_mfma_f32_16x16x32_bf16(ah[i], bh[j], acc[i][j], 0, 0, 0);
                acc[i][j] = __builtin_amdgcn_mfma_f32_16x16x32_bf16(ah[i], bl[j], acc[i][j], 0, 0, 0);
                acc[i][j] = __builtin_amdgcn_mfma_f32_16x16x32_bf16(al[i], bh[j], acc[i][j], 0, 0, 0);
            }
        __syncthreads();
    }
    float* outp = P + z * 524288;
#pragma unroll
    for (int i = 0; i < 2; ++i)
#pragma unroll
        for (int j = 0; j < 2; ++j) {
            int rbase = (it0 + 2 * wr + i) * 16 + (lane >> 4) * 4;
            int c = (nt0 + 2 * wc + j) * 16 + (lane & 15);
#pragma unroll
            for (int r = 0; r < 4; ++r)
                outp[(size_t)(rbase + r) * 1024 + c] = acc[i][j][r];
        }
}

// ---------- K7: GAT1 epilogue: sum 4 partials + geom rows + a_s1/a_d1 ----------
__global__ __launch_bounds__(256) void k_gat1ep(const float* __restrict__ P,
                                                const float* __restrict__ boxesf,
                                                const float* __restrict__ Wg,
                                                const float* __restrict__ asrcf,
                                                const float* __restrict__ adstf,
                                                float* __restrict__ hX,
                                                float* __restrict__ a_s1,
                                                float* __restrict__ a_d1) {
    int i = blockIdx.x, t = threadIdx.x;
    const float* P0 = P;
    const float* P1 = P + 524288;
    const float* P2 = P + 1048576;
    const float* P3 = P + 1572864;
    float4 bx = *(const float4*)(boxesf + i * 4);
    float g0 = bx.x / 800.f, g1 = bx.y / 800.f;
    float g2 = bx.z / 800.f - g0, g3 = bx.w / 800.f - g1;
    float ps[4], pd[4];
#pragma unroll
    for (int q = 0; q < 4; ++q) {
        int c = q * 256 + t;
        float v = P0[i * 1024 + c] + P1[i * 1024 + c] + P2[i * 1024 + c] + P3[i * 1024 + c];
        v = fmaf(g0, Wg[1024 * 1024 + c], v);
        v = fmaf(g1, Wg[1025 * 1024 + c], v);
        v = fmaf(g2, Wg[1026 * 1024 + c], v);
        v = fmaf(g3, Wg[1027 * 1024 + c], v);
        hX[i * 1024 + c] = v;          // in-place over P0 row i (same thread RAW only)
        ps[q] = v * asrcf[c];
        pd[q] = v * adstf[c];
    }
    __shared__ float rs[4][4], rd[4][4];
    int wid = t >> 6;
#pragma unroll
    for (int off = 32; off > 0; off >>= 1) {
#pragma unroll
        for (int q = 0; q < 4; ++q) {
            ps[q] += __shfl_down(ps[q], off);
            pd[q] += __shfl_down(pd[q], off);
        }
    }
    if ((t & 63) == 0) {
#pragma unroll
        for (int q = 0; q < 4; ++q) { rs[wid][q] = ps[q]; rd[wid][q] = pd[q]; }
    }
    __syncthreads();
    if (t < 4)
        a_s1[i * 4 + t] = rs[0][t] + rs[1][t] + rs[2][t] + rs[3][t];
    else if (t < 8) {
        int q = t - 4;
        a_d1[i * 4 + q] = rd[0][q] + rd[1][q] + rd[2][q] + rd[3][q];
    }
}

// ---------- K8: GAT1 per-dst softmax + aggregate + bias + relu ----------
__global__ void k_aggr1(const float* __restrict__ hX,
                        const float* __restrict__ a_s, const float* __restrict__ a_d,
                        const int* __restrict__ offs, const int* __restrict__ inlist,
                        const float* __restrict__ bias,
                        float* __restrict__ h1) {
    int n = blockIdx.x, t = threadIdx.x;
    int beg = offs[n], deg = offs[n + 1] - beg;
    if (deg > 513) deg = 513;
    __shared__ int srcs[520];
    __shared__ float alpha[520][4];
    __shared__ float sm[4];
    for (int e = t; e < deg; e += 256) srcs[e] = inlist[beg + e] & 511;
    __syncthreads();
    for (int idx = t; idx < deg * 4; idx += 256) {
        int e = idx >> 2, q = idx & 3;
        float sc = a_s[srcs[e] * 4 + q] + a_d[n * 4 + q];
        alpha[e][q] = (sc >= 0.f) ? sc : 0.2f * sc;
    }
    __syncthreads();
    if (t < 4) {
        float m = -INFINITY;
        for (int e = 0; e < deg; ++e) m = fmaxf(m, alpha[e][t]);
        if (!isfinite(m)) m = 0.f;
        float s = 0.f;
        for (int e = 0; e < deg; ++e) { float ex = expf(alpha[e][t] - m); alpha[e][t] = ex; s += ex; }
        sm[t] = s + 1e-16f;
    }
    __syncthreads();
    for (int idx = t; idx < deg * 4; idx += 256) {
        int e = idx >> 2, q = idx & 3;
        alpha[e][q] /= sm[q];
    }
    __syncthreads();
    for (int q = 0; q < 4; ++q) {
        float acc = 0.f;
        for (int e = 0; e < deg; ++e) acc += alpha[e][q] * hX[srcs[e] * 1024 + q * 256 + t];
        h1[n * 1024 + q * 256 + t] = fmaxf(acc + bias[q * 256 + t], 0.f);
    }
}

// ---------- K9: GAT2 GEMM + a_s2/a_d2 (2-way K-split, 4 accums) ----------
__global__ __launch_bounds__(256) void k_gat2(const float* __restrict__ h1,
                                              const float* __restrict__ Wf,
                                              const float* __restrict__ asrcf,
                                              const float* __restrict__ adstf,
                                              float* __restrict__ h2,
                                              float* __restrict__ a_s2,
                                              float* __restrict__ a_d2) {
    int n = blockIdx.x, t = threadIdx.x;
    __shared__ float xs[1024];
    __shared__ float hbuf[NCLS];
    __shared__ float sred[256], dred[256];
    for (int c = t; c < 1024; c += 256) xs[c] = h1[n * 1024 + c];
    __syncthreads();
    int cls = t & 127, kh = t >> 7;
    float acc = 0.f;
    if (cls < NCLS) {
        const float* wp = Wf + (kh * 512) * NCLS + cls;
        const float* xp = xs + kh * 512;
        float a0 = 0.f, a1 = 0.f, a2 = 0.f, a3 = 0.f;
        for (int c = 0; c < 512; c += 4) {
            a0 = fmaf(xp[c + 0], wp[(c + 0) * NCLS], a0);
            a1 = fmaf(xp[c + 1], wp[(c + 1) * NCLS], a1);
            a2 = fmaf(xp[c + 2], wp[(c + 2) * NCLS], a2);
            a3 = fmaf(xp[c + 3], wp[(c + 3) * NCLS], a3);
        }
        acc = (a0 + a1) + (a2 + a3);
    }
    if (kh == 0 && cls < NCLS) hbuf[cls] = acc;
    __syncthreads();
    float tot = 0.f;
    int act = (kh == 1 && cls < NCLS);
    if (act) { tot = acc + hbuf[cls]; h2[n * NCLS + cls] = tot; }
    sred[t] = act ? tot * asrcf[cls] : 0.f;
    dred[t] = act ? tot * adstf[cls] : 0.f;
    __syncthreads();
    for (int s = 128; s > 0; s >>= 1) {
        if (t < s) { sred[t] += sred[t + s]; dred[t] += dred[t + s]; }
        __syncthreads();
    }
    if (t == 0) { a_s2[n] = sred[0]; a_d2[n] = dred[0]; }
}

// ---------- K10: GAT2 aggregate -> logits + softmax probs ----------
__global__ void k_aggr2(const float* __restrict__ h2,
                        const float* __restrict__ a_s2, const float* __restrict__ a_d2,
                        const int* __restrict__ offs, const int* __restrict__ inlist,
                        const float* __restrict__ bias,
                        float* __restrict__ logits_out,
                        float* __restrict__ probs_out) {
    int n = blockIdx.x, t = threadIdx.x;
    int beg = offs[n], deg = offs[n + 1] - beg;
    if (deg > 513) deg = 513;
    __shared__ int srcs[520];
    __shared__ float alpha[520];
    __shared__ float red[128];
    __shared__ float smden;
    for (int e = t; e < deg; e += 128) {
        int s = inlist[beg + e] & 511;
        srcs[e] = s;
        float sc = a_s2[s] + a_d2[n];
        alpha[e] = (sc >= 0.f) ? sc : 0.2f * sc;
    }
    __syncthreads();
    if (t == 0) {
        float m = -INFINITY;
        for (int e = 0; e < deg; ++e) m = fmaxf(m, alpha[e]);
        if (!isfinite(m)) m = 0.f;
        float s = 0.f;
        for (int e = 0; e < deg; ++e) { float ex = expf(alpha[e] - m); alpha[e] = ex; s += ex; }
        smden = s + 1e-16f;
    }
    __syncthreads();
    float logit = 0.f;
    if (t < NCLS) {
        float acc = 0.f;
        for (int e = 0; e < deg; ++e) acc += alpha[e] * h2[srcs[e] * NCLS + t];
        logit = acc / smden + bias[t];
        logits_out[n * NCLS + t] = logit;
    }
    red[t] = (t < NCLS) ? logit : -INFINITY; __syncthreads();
    for (int s = 64; s > 0; s >>= 1) { if (t < s) red[t] = fmaxf(red[t], red[t + s]); __syncthreads(); }
    float mx = red[0];
    __syncthreads();
    float ex = (t < NCLS) ? expf(logit - mx) : 0.f;
    red[t] = ex; __syncthreads();
    for (int s = 64; s > 0; s >>= 1) { if (t < s) red[t] += red[t + s]; __syncthreads(); }
    float inv = 1.f / red[0];
    if (t < NCLS) probs_out[n * NCLS + t] = ex * inv;
}

// ---------- launch ----------
extern "C" void kernel_launch(void* const* d_in, const int* in_sizes, int n_in,
                              void* d_out, int out_size, void* d_ws, size_t ws_size,
                              hipStream_t stream) {
    const float* feats   = (const float*)d_in[0];
    const float* boxes   = (const float*)d_in[1];
    const float* repn_w1 = (const float*)d_in[2];
    const float* repn_b1 = (const float*)d_in[3];
    const float* repn_w2 = (const float*)d_in[4];
    const float* repn_b2 = (const float*)d_in[5];
    const float* gat1_w    = (const float*)d_in[6];
    const float* gat1_asrc = (const float*)d_in[7];
    const float* gat1_adst = (const float*)d_in[8];
    const float* gat1_b    = (const float*)d_in[9];
    const float* gat2_w    = (const float*)d_in[10];
    const float* gat2_asrc = (const float*)d_in[11];
    const float* gat2_adst = (const float*)d_in[12];
    const float* gat2_b    = (const float*)d_in[13];
    const int* kp = (const int*)d_in[14];

    float* out = (float*)d_out;
    float* logits_out = out;
    float* probs_out  = out + 512 * NCLS;
    float* rel_out    = out + 2 * 512 * NCLS;

    // Workspace map (floats):
    //  [0,2097152)        pp: 8 x 512x512 p12 partials (p12 -> psum); then
    //                     P: 4 x 512x1024 gat1 MFMA partials aliased here (mm1 -> gat1ep);
    //                     hX aliases P0 (gat1ep -> aggr1); h1 aliases P1 (aggr1 -> gat2)
    //  [2097152,2359296)  ppsum: collapsed p12 result (psum -> rel)
    //  [2359296,3145728)  prel: 3 rel partials (z=1..3), live rel -> topk
    //  [3145728,4718592)  bf16 frag arrays: Afh, Afl (262144 floats each),
    //                     Bfh, Bfl (524288 floats each)
    //  [4718592, ...)     h2 / a_s2 / a_d2 / a_s1 / a_d1 / int block
    float* wsf   = (float*)d_ws;
    float* pp    = wsf;
    float* P     = wsf;                 // alias pp (mm1 launches after k_rel)
    float* hX    = P;
    float* h1    = P + 524288;
    float* ppsum = wsf + 2097152;
    float* prel  = wsf + 2359296;
    ushort* Afh  = (ushort*)(wsf + 3145728);
    ushort* Afl  = (ushort*)(wsf + 3407872);
    ushort* Bfh  = (ushort*)(wsf + 3670016);
    ushort* Bfl  = (ushort*)(wsf + 4194304);
    float* h2    = wsf + 4718592;       // 46592, pad to 47104
    float* a_s2  = wsf + 4765696;
    float* a_d2  = wsf + 4766208;
    float* a_s1  = wsf + 4766720;
    float* a_d1  = wsf + 4768768;
    int* ib      = (int*)(wsf + 4770816);
    int* count   = ib;                  // 512 (zeroed by k_conv)
    int* nbrs    = ib + 1024;           // 4096
    int* offs    = ib + 5120;           // 520
    int* inlist  = ib + 5640;           // 4096

    k_conv<<<dim3(768), dim3(256), 0, stream>>>(feats, gat1_w, Afh, Afl, Bfh, Bfl, ib);
    k_p12<<<dim3(8, 16, 8), dim3(128), 0, stream>>>(feats, repn_w1, pp);
    k_psum<<<dim3(256), dim3(256), 0, stream>>>(pp, ppsum);
    k_rel<<<dim3(8, 32, 4), dim3(256), 0, stream>>>(ppsum, repn_w1, repn_b1, repn_w2,
                                                    boxes, rel_out, prel);
    k_topk<<<dim3(512), dim3(64), 0, stream>>>(rel_out, prel, repn_b2, kp,
                                               nbrs, count, rel_out);
    k_scanfill<<<dim3(1), dim3(512), 0, stream>>>(count, nbrs, kp, offs, inlist);
    k_mm1<<<dim3(16, 8, 4), dim3(256), 0, stream>>>(Afh, Afl, Bfh, Bfl, P);
    k_gat1ep<<<dim3(512), dim3(256), 0, stream>>>(P, boxes, gat1_w, gat1_asrc,
                                                  gat1_adst, hX, a_s1, a_d1);
    k_aggr1<<<dim3(512), dim3(256), 0, stream>>>(hX, a_s1, a_d1, offs, inlist, gat1_b, h1);
    k_gat2<<<dim3(512), dim3(256), 0, stream>>>(h1, gat2_w, gat2_asrc, gat2_adst,
                                                h2, a_s2, a_d2);
    k_aggr2<<<dim3(512), dim3(128), 0, stream>>>(h2, a_s2, a_d2, offs, inlist, gat2_b,
                                                 logits_out, probs_out);
}

// Round 7
// 179.006 us; speedup vs baseline: 1.1401x; 1.0389x over previous
//
#include <hip/hip_runtime.h>

// Inputs and outputs are float32 (established R1/R3).
#define NCLS 91
#define W1_LD 2052   // repn_w1 row length (2C+4)

typedef __attribute__((ext_vector_type(8))) short short8;   // 8 bf16 (4 VGPRs)
typedef __attribute__((ext_vector_type(4))) float f32x4;    // MFMA C/D

__device__ inline ushort bf16_rne(float x) {
    unsigned u = __float_as_uint(x);
    return (ushort)((u + 0x7fffu + ((u >> 16) & 1u)) >> 16);
}

// ---------- K1: fused conv (bf16 frag split) + p12 partial GEMM ----------
// blocks 0..511:    conv-A  (feats -> Afh/Afl frag layout), b<4 also zero count
// blocks 512..1535: conv-B  (gat1_w K-rows -> Bfh/Bfl frag layout)
// blocks 1536..2559: p12    p_part[z][i][r] = feats[i, z*128:+128].Wcomb[r, z*128:+128]
//                    (Wcomb rows 0..255 = wf1, 256..511 = wf2; decode (8 r,16 i,8 z))
__global__ __launch_bounds__(128) void k_pre(const float* __restrict__ feats,
                                             const float* __restrict__ Wg,
                                             ushort* __restrict__ Afh,
                                             ushort* __restrict__ Afl,
                                             ushort* __restrict__ Bfh,
                                             ushort* __restrict__ Bfl,
                                             int* __restrict__ zero_ints,
                                             const float* __restrict__ w1f,
                                             float* __restrict__ pp) {
    int b = blockIdx.x, tid = threadIdx.x;
    __shared__ float As[64 * 32];   // [k][i]  (p12 branch only)
    __shared__ float Bs[64 * 64];   // [k][r]
    if (b < 1536) {
        // ---- conv branch ----
        if (b < 4) zero_ints[b * 128 + tid] = 0;
        int lane = tid & 63;
        float x[8];
        size_t off;
        ushort *oh, *ol;
        if (b < 512) {   // A: 512 blocks x 128 thr = 65536 lane-items = 32 it x 32 kt x 64
            int g = b * 128 + tid;
            int q = g >> 6;
            int it = q & 31, kt = q >> 5;
            int row = it * 16 + (lane & 15);
            int col0 = kt * 32 + (lane >> 4) * 8;
            const float* src = feats + row * 1024 + col0;
            float4 u0 = *(const float4*)(src);
            float4 u1 = *(const float4*)(src + 4);
            x[0] = u0.x; x[1] = u0.y; x[2] = u0.z; x[3] = u0.w;
            x[4] = u1.x; x[5] = u1.y; x[6] = u1.z; x[7] = u1.w;
            off = ((size_t)(kt * 32 + it) * 64 + lane) * 8;
            oh = Afh; ol = Afl;
        } else {          // B: 1024 blocks = 32 kt x 64 nt x 64 lanes
            int g = (b - 512) * 128 + tid;
            int q = g >> 6;
            int nt = q & 63, kt = q >> 6;
            int col = nt * 16 + (lane & 15);
            int row0 = kt * 32 + (lane >> 4) * 8;
#pragma unroll
            for (int e = 0; e < 8; ++e) x[e] = Wg[(row0 + e) * 1024 + col];
            off = ((size_t)(kt * 64 + nt) * 64 + lane) * 8;
            oh = Bfh; ol = Bfl;
        }
        uint uh[4], ul[4];
#pragma unroll
        for (int p = 0; p < 4; ++p) {
            ushort h0 = bf16_rne(x[2 * p]);
            ushort h1 = bf16_rne(x[2 * p + 1]);
            float f0 = __uint_as_float((unsigned)h0 << 16);
            float f1 = __uint_as_float((unsigned)h1 << 16);
            ushort l0 = bf16_rne(x[2 * p] - f0);
            ushort l1 = bf16_rne(x[2 * p + 1] - f1);
            uh[p] = (uint)h0 | ((uint)h1 << 16);
            ul[p] = (uint)l0 | ((uint)l1 << 16);
        }
        *(uint4*)(oh + off) = make_uint4(uh[0], uh[1], uh[2], uh[3]);
        *(uint4*)(ol + off) = make_uint4(ul[0], ul[1], ul[2], ul[3]);
        return;
    }
    // ---- p12 branch ----
    int bx = b - 1536;
    int r0 = (bx & 7) * 64, i0 = ((bx >> 3) & 15) * 32, z = bx >> 7;
    int tx = tid & 15, ty = tid >> 4;
    float* pout = pp + z * 262144;
    int ai = tid & 31, akq = (tid >> 5) * 16;          // A loader: 4 float4 along k
    int br = tid & 63, bkq = (tid >> 6) * 32;          // B loader: 8 float4 along k
    const float* abase = feats + (i0 + ai) * 1024 + z * 128 + akq;
    int rg = r0 + br;
    const float* bbase = w1f + (rg < 256 ? rg * W1_LD : (rg - 256) * W1_LD + 1024)
                       + z * 128 + bkq;
    float4 av[4], bv[8];
#pragma unroll
    for (int s = 0; s < 4; ++s) av[s] = *(const float4*)(abase + 4 * s);
#pragma unroll
    for (int s = 0; s < 8; ++s) bv[s] = *(const float4*)(bbase + 4 * s);
    float acc[4][4] = {};
    for (int kt = 0; kt < 2; ++kt) {
#pragma unroll
        for (int s = 0; s < 4; ++s) {   // transpose store: lanes distinct ai -> 2-way max
            int k = akq + 4 * s;
            As[(k + 0) * 32 + ai] = av[s].x; As[(k + 1) * 32 + ai] = av[s].y;
            As[(k + 2) * 32 + ai] = av[s].z; As[(k + 3) * 32 + ai] = av[s].w;
        }
#pragma unroll
        for (int s = 0; s < 8; ++s) {   // transpose store: lanes distinct br -> 2-way max
            int k = bkq + 4 * s;
            Bs[(k + 0) * 64 + br] = bv[s].x; Bs[(k + 1) * 64 + br] = bv[s].y;
            Bs[(k + 2) * 64 + br] = bv[s].z; Bs[(k + 3) * 64 + br] = bv[s].w;
        }
        __syncthreads();
        if (kt + 1 < 2) {
#pragma unroll
            for (int s = 0; s < 4; ++s) av[s] = *(const float4*)(abase + 64 + 4 * s);
#pragma unroll
            for (int s = 0; s < 8; ++s) bv[s] = *(const float4*)(bbase + 64 + 4 * s);
        }
#pragma unroll
        for (int k = 0; k < 64; ++k) {
            float4 a4 = *(const float4*)(As + k * 32 + ty * 4);
            float4 b4 = *(const float4*)(Bs + k * 64 + tx * 4);
            acc[0][0] = fmaf(a4.x, b4.x, acc[0][0]); acc[0][1] = fmaf(a4.x, b4.y, acc[0][1]);
            acc[0][2] = fmaf(a4.x, b4.z, acc[0][2]); acc[0][3] = fmaf(a4.x, b4.w, acc[0][3]);
            acc[1][0] = fmaf(a4.y, b4.x, acc[1][0]); acc[1][1] = fmaf(a4.y, b4.y, acc[1][1]);
            acc[1][2] = fmaf(a4.y, b4.z, acc[1][2]); acc[1][3] = fmaf(a4.y, b4.w, acc[1][3]);
            acc[2][0] = fmaf(a4.z, b4.x, acc[2][0]); acc[2][1] = fmaf(a4.z, b4.y, acc[2][1]);
            acc[2][2] = fmaf(a4.z, b4.z, acc[2][2]); acc[2][3] = fmaf(a4.z, b4.w, acc[2][3]);
            acc[3][0] = fmaf(a4.w, b4.x, acc[3][0]); acc[3][1] = fmaf(a4.w, b4.y, acc[3][1]);
            acc[3][2] = fmaf(a4.w, b4.z, acc[3][2]); acc[3][3] = fmaf(a4.w, b4.w, acc[3][3]);
        }
        __syncthreads();
    }
#pragma unroll
    for (int ii = 0; ii < 4; ++ii)
        *(float4*)(pout + (i0 + ty * 4 + ii) * 512 + r0 + tx * 4) =
            make_float4(acc[ii][0], acc[ii][1], acc[ii][2], acc[ii][3]);
}

// ---------- K1b: collapse 8 pp partials -> ppsum (pure streaming, 9 MB) ----------
__global__ __launch_bounds__(256) void k_psum(const float* __restrict__ pp,
                                              float* __restrict__ ppsum) {
    int idx = (blockIdx.x * 256 + threadIdx.x) * 4;
    float4 a = *(const float4*)(pp + idx);
#pragma unroll
    for (int p = 1; p < 8; ++p) {
        float4 v = *(const float4*)(pp + p * 262144 + idx);
        a.x += v.x; a.y += v.y; a.z += v.z; a.w += v.w;
    }
    *(float4*)(ppsum + idx) = a;
}

// ---------- K2: fused rel partials (blocks 0..1023) + GAT1 MFMA GEMM (1024..1535) ----
// rel: h-chunk split 4-way across z; decode (8 j, 32 i, 4 z); ppsum L2-resident.
//      z=0 partial -> r0 (rel_out scratch), z>0 -> prel[z-1]. Final sum+b2 in k_topk.
// mm1: bf16 MFMA 2-term (hh+hl+lh); decode (16 n, 8 i, 4 z); partial -> P[z].
// LDS shared via union (32 KB -> up to 5 blocks/CU).
__global__ __launch_bounds__(256) void k_relmm(const float* __restrict__ ppsum,
                                               const float* __restrict__ w1f,
                                               const float* __restrict__ b1f,
                                               const float* __restrict__ w2f,
                                               const float* __restrict__ boxesf,
                                               float* __restrict__ r0,
                                               float* __restrict__ prel,
                                               const ushort* __restrict__ Afh,
                                               const ushort* __restrict__ Afl,
                                               const ushort* __restrict__ Bfh,
                                               const ushort* __restrict__ Bfl,
                                               float* __restrict__ P) {
    __shared__ union SM {
        struct { float As1[32 * 17]; float Bs[32 * 64]; float Awg[32 * 4]; float Aw2[32]; } r;
        uint4 buf[2][4][4][64];   // [dbuf][Ah Al Bh Bl][sub][lane]
    } sm;
    int b = blockIdx.x;
    if (b < 1024) {
        // ---- rel branch ----
        int j0 = (b & 7) * 64, i0 = ((b >> 3) & 31) * 16, z = b >> 8;
        int tid = threadIdx.x, tx = tid & 63, ty = tid >> 6;
        float* As1 = sm.r.As1;
        float* Bs  = sm.r.Bs;
        float* Awg = sm.r.Awg;
        float* Aw2 = sm.r.Aw2;
        float4 bj = *(const float4*)(boxesf + (j0 + tx) * 4);
        float g[4][4];
#pragma unroll
        for (int s = 0; s < 4; ++s) {
            float4 bi = *(const float4*)(boxesf + (i0 + ty * 4 + s) * 4);
            g[s][0] = fabsf(bi.x - bj.x); g[s][1] = fabsf(bi.y - bj.y);
            g[s][2] = fabsf(bi.z - bj.z); g[s][3] = fabsf(bi.w - bj.w);
        }
        float acc[4] = {0.f, 0.f, 0.f, 0.f};
        int ali = tid & 15, alh = (tid >> 4) * 4;     // tid<128: one float4 along h
        int blj = tid & 63, blh = (tid >> 6) * 8;     // 2 float4 along h
        for (int c4 = 0; c4 < 2; ++c4) {
            int hb = (z * 2 + c4) * 32;
            if (tid < 128) {
                float4 a4 = *(const float4*)(ppsum + (i0 + ali) * 512 + hb + alh);
                float4 bb = *(const float4*)(b1f + hb + alh);
                As1[(alh + 0) * 17 + ali] = a4.x + bb.x;
                As1[(alh + 1) * 17 + ali] = a4.y + bb.y;
                As1[(alh + 2) * 17 + ali] = a4.z + bb.z;
                As1[(alh + 3) * 17 + ali] = a4.w + bb.w;
            }
#pragma unroll
            for (int s = 0; s < 2; ++s) {
                int h = blh + 4 * s;
                float4 u4 = *(const float4*)(ppsum + (j0 + blj) * 512 + 256 + hb + h);
                Bs[(h + 0) * 64 + blj] = u4.x;
                Bs[(h + 1) * 64 + blj] = u4.y;
                Bs[(h + 2) * 64 + blj] = u4.z;
                Bs[(h + 3) * 64 + blj] = u4.w;
            }
            if (tid < 32) {
                int hg = hb + tid;
                *(float4*)(Awg + tid * 4) = *(const float4*)(w1f + hg * W1_LD + 2048);
                Aw2[tid] = w2f[hg];
            }
            __syncthreads();
#pragma unroll
            for (int hh = 0; hh < 32; ++hh) {
                float4 wg = *(const float4*)(Awg + hh * 4);
                float w2v = Aw2[hh];
                float p2v = Bs[hh * 64 + tx];
                float s0 = As1[hh * 17 + ty * 4 + 0];
                float s1 = As1[hh * 17 + ty * 4 + 1];
                float s2 = As1[hh * 17 + ty * 4 + 2];
                float s3 = As1[hh * 17 + ty * 4 + 3];
                float t0 = s0 + p2v;
                t0 = fmaf(g[0][0], wg.x, t0); t0 = fmaf(g[0][1], wg.y, t0);
                t0 = fmaf(g[0][2], wg.z, t0); t0 = fmaf(g[0][3], wg.w, t0);
                acc[0] = fmaf(w2v, fmaxf(t0, 0.f), acc[0]);
                float t1 = s1 + p2v;
                t1 = fmaf(g[1][0], wg.x, t1); t1 = fmaf(g[1][1], wg.y, t1);
                t1 = fmaf(g[1][2], wg.z, t1); t1 = fmaf(g[1][3], wg.w, t1);
                acc[1] = fmaf(w2v, fmaxf(t1, 0.f), acc[1]);
                float t2 = s2 + p2v;
                t2 = fmaf(g[2][0], wg.x, t2); t2 = fmaf(g[2][1], wg.y, t2);
                t2 = fmaf(g[2][2], wg.z, t2); t2 = fmaf(g[2][3], wg.w, t2);
                acc[2] = fmaf(w2v, fmaxf(t2, 0.f), acc[2]);
                float t3 = s3 + p2v;
                t3 = fmaf(g[3][0], wg.x, t3); t3 = fmaf(g[3][1], wg.y, t3);
                t3 = fmaf(g[3][2], wg.z, t3); t3 = fmaf(g[3][3], wg.w, t3);
                acc[3] = fmaf(w2v, fmaxf(t3, 0.f), acc[3]);
            }
            __syncthreads();
        }
        float* po = (z == 0) ? r0 : (prel + (z - 1) * 262144);
#pragma unroll
        for (int s = 0; s < 4; ++s)
            po[(i0 + ty * 4 + s) * 512 + j0 + tx] = acc[s];
        return;
    }
    // ---- mm1 branch ----
    int m = b - 1024;
    int nt0 = (m & 15) * 4, it0 = ((m >> 4) & 7) * 4, z = m >> 7;
    int t = threadIdx.x, lane = t & 63, w = t >> 6;
    int wr = w >> 1, wc = w & 1, sub = w;
    const uint4* gAh = (const uint4*)Afh;
    const uint4* gAl = (const uint4*)Afl;
    const uint4* gBh = (const uint4*)Bfh;
    const uint4* gBl = (const uint4*)Bfl;
    f32x4 acc[2][2];
    f32x4 zero = {0.f, 0.f, 0.f, 0.f};
    acc[0][0] = zero; acc[0][1] = zero; acc[1][0] = zero; acc[1][1] = zero;
    int ktg = z * 8;
    uint4 rah = gAh[(ktg * 32 + it0 + sub) * 64 + lane];
    uint4 ral = gAl[(ktg * 32 + it0 + sub) * 64 + lane];
    uint4 rbh = gBh[(ktg * 64 + nt0 + sub) * 64 + lane];
    uint4 rbl = gBl[(ktg * 64 + nt0 + sub) * 64 + lane];
    for (int kk = 0; kk < 8; ++kk) {
        int cur = kk & 1;
        sm.buf[cur][0][sub][lane] = rah;
        sm.buf[cur][1][sub][lane] = ral;
        sm.buf[cur][2][sub][lane] = rbh;
        sm.buf[cur][3][sub][lane] = rbl;
        __syncthreads();
        if (kk < 7) {
            int kn = ktg + kk + 1;
            rah = gAh[(kn * 32 + it0 + sub) * 64 + lane];
            ral = gAl[(kn * 32 + it0 + sub) * 64 + lane];
            rbh = gBh[(kn * 64 + nt0 + sub) * 64 + lane];
            rbl = gBl[(kn * 64 + nt0 + sub) * 64 + lane];
        }
        short8 ah[2], al[2], bh[2], bl[2];
#pragma unroll
        for (int i = 0; i < 2; ++i) {
            ah[i] = *(const short8*)&sm.buf[cur][0][2 * wr + i][lane];
            al[i] = *(const short8*)&sm.buf[cur][1][2 * wr + i][lane];
            bh[i] = *(const short8*)&sm.buf[cur][2][2 * wc + i][lane];
            bl[i] = *(const short8*)&sm.buf[cur][3][2 * wc + i][lane];
        }
#pragma unroll
        for (int i = 0; i < 2; ++i)
#pragma unroll
            for (int j = 0; j < 2; ++j) {
                acc[i][j] = __builtin_amdgcn_mfma_f32_16x16x32_bf16(ah[i], bh[j], acc[i][j], 0, 0, 0);
                acc[i][j] = __builtin_amdgcn_mfma_f32_16x16x32_bf16(ah[i], bl[j], acc[i][j], 0, 0, 0);
                acc[i][j] = __builtin_amdgcn_mfma_f32_16x16x32_bf16(al[i], bh[j], acc[i][j], 0, 0, 0);
            }
        __syncthreads();
    }
    float* outp = P + z * 524288;
#pragma unroll
    for (int i = 0; i < 2; ++i)
#pragma unroll
        for (int j = 0; j < 2; ++j) {
            int rbase = (it0 + 2 * wr + i) * 16 + (lane >> 4) * 4;
            int c = (nt0 + 2 * wc + j) * 16 + (lane & 15);
#pragma unroll
            for (int r = 0; r < 4; ++r)
                outp[(size_t)(rbase + r) * 1024 + c] = acc[i][j][r];
        }
}

// ---------- K3: sum 4 rel partials + b2 -> rel_out; per-row top-(k+1); in-degrees ----------
__global__ void k_topk(const float* __restrict__ r0, const float* __restrict__ prel,
                       const float* __restrict__ b2f, const int* __restrict__ kp,
                       int* __restrict__ nbrs, int* __restrict__ count,
                       float* __restrict__ rel_out) {
    int i = blockIdx.x, lane = threadIdx.x;
    int k = *kp;
    float b2v = b2f[0];
    float v[8]; int ids[8];
    for (int q = 0; q < 8; ++q) {
        int j = lane + 64 * q;
        float val = r0[i * 512 + j] + prel[i * 512 + j]
                  + prel[262144 + i * 512 + j] + prel[524288 + i * 512 + j] + b2v;
        rel_out[i * 512 + j] = val;   // same thread reads then writes this slot
        v[q] = val;
        ids[q] = j;
    }
    for (int pick = 0; pick < k + 1; ++pick) {
        float bv = -INFINITY; int bidx = 1 << 30;
        for (int q = 0; q < 8; ++q)
            if (v[q] > bv || (v[q] == bv && ids[q] < bidx)) { bv = v[q]; bidx = ids[q]; }
        for (int off = 32; off > 0; off >>= 1) {
            float ov = __shfl_down(bv, off);
            int oi = __shfl_down(bidx, off);
            if (ov > bv || (ov == bv && oi < bidx)) { bv = ov; bidx = oi; }
        }
        bv = __shfl(bv, 0); bidx = __shfl(bidx, 0);
        if (pick >= 1 && lane == 0) {
            nbrs[i * 8 + (pick - 1)] = bidx;
            atomicAdd(&count[bidx], 1);
        }
        for (int q = 0; q < 8; ++q) if (ids[q] == bidx) v[q] = -INFINITY;
    }
    if (lane == 0) atomicAdd(&count[i], 1);
}

// ---------- K5: fused GAT1 epilogue (blocks 0..511) + scan/fill (block 512) ----------
__global__ __launch_bounds__(256) void k_epsf(const float* __restrict__ P,
                                              const float* __restrict__ boxesf,
                                              const float* __restrict__ Wg,
                                              const float* __restrict__ asrcf,
                                              const float* __restrict__ adstf,
                                              float* __restrict__ hX,
                                              float* __restrict__ a_s1,
                                              float* __restrict__ a_d1,
                                              const int* __restrict__ count,
                                              const int* __restrict__ nbrs,
                                              const int* __restrict__ kp,
                                              int* __restrict__ offs,
                                              int* __restrict__ inlist) {
    __shared__ int ss[512], excl[512], cur[512];
    __shared__ float rs[4][4], rd[4][4];
    int t = threadIdx.x;
    if (blockIdx.x == 512) {
        // ---- scan + fill (256 thr, 2 nodes each) ----
        int c0 = count[t], c1 = count[t + 256];
        ss[t] = c0; ss[t + 256] = c1; cur[t] = 0; cur[t + 256] = 0;
        __syncthreads();
        for (int off = 1; off < 512; off <<= 1) {
            int v0 = (t >= off) ? ss[t - off] : 0;
            int v1 = (t + 256 >= off) ? ss[t + 256 - off] : 0;
            __syncthreads();
            ss[t] += v0; ss[t + 256] += v1;
            __syncthreads();
        }
        offs[t + 1] = ss[t];
        offs[t + 257] = ss[t + 256];
        if (t == 0) offs[0] = 0;
        excl[t] = ss[t] - c0;
        excl[t + 256] = ss[t + 256] - c1;
        __syncthreads();
        int k = *kp;
#pragma unroll
        for (int h = 0; h < 2; ++h) {
            int node = t + h * 256;
            for (int q = 0; q < k; ++q) {
                int d = nbrs[node * 8 + q] & 511;
                int pos = atomicAdd(&cur[d], 1);
                inlist[excl[d] + pos] = node;
            }
            int pos = atomicAdd(&cur[node], 1);
            inlist[excl[node] + pos] = node;
        }
        return;
    }
    // ---- gat1ep: sum 4 partials + geom rows + a_s1/a_d1 ----
    int i = blockIdx.x;
    const float* P0 = P;
    const float* P1 = P + 524288;
    const float* P2 = P + 1048576;
    const float* P3 = P + 1572864;
    float4 bx = *(const float4*)(boxesf + i * 4);
    float g0 = bx.x / 800.f, g1 = bx.y / 800.f;
    float g2 = bx.z / 800.f - g0, g3 = bx.w / 800.f - g1;
    float ps[4], pd[4];
#pragma unroll
    for (int q = 0; q < 4; ++q) {
        int c = q * 256 + t;
        float v = P0[i * 1024 + c] + P1[i * 1024 + c] + P2[i * 1024 + c] + P3[i * 1024 + c];
        v = fmaf(g0, Wg[1024 * 1024 + c], v);
        v = fmaf(g1, Wg[1025 * 1024 + c], v);
        v = fmaf(g2, Wg[1026 * 1024 + c], v);
        v = fmaf(g3, Wg[1027 * 1024 + c], v);
        hX[i * 1024 + c] = v;          // in-place over P0 row i (same thread RAW only)
        ps[q] = v * asrcf[c];
        pd[q] = v * adstf[c];
    }
    int wid = t >> 6;
#pragma unroll
    for (int off = 32; off > 0; off >>= 1) {
#pragma unroll
        for (int q = 0; q < 4; ++q) {
            ps[q] += __shfl_down(ps[q], off);
            pd[q] += __shfl_down(pd[q], off);
        }
    }
    if ((t & 63) == 0) {
#pragma unroll
        for (int q = 0; q < 4; ++q) { rs[wid][q] = ps[q]; rd[wid][q] = pd[q]; }
    }
    __syncthreads();
    if (t < 4)
        a_s1[i * 4 + t] = rs[0][t] + rs[1][t] + rs[2][t] + rs[3][t];
    else if (t < 8) {
        int q = t - 4;
        a_d1[i * 4 + q] = rd[0][q] + rd[1][q] + rd[2][q] + rd[3][q];
    }
}

// ---------- K8: GAT1 per-dst softmax + aggregate + bias + relu ----------
__global__ void k_aggr1(const float* __restrict__ hX,
                        const float* __restrict__ a_s, const float* __restrict__ a_d,
                        const int* __restrict__ offs, const int* __restrict__ inlist,
                        const float* __restrict__ bias,
                        float* __restrict__ h1) {
    int n = blockIdx.x, t = threadIdx.x;
    int beg = offs[n], deg = offs[n + 1] - beg;
    if (deg > 513) deg = 513;
    __shared__ int srcs[520];
    __shared__ float alpha[520][4];
    __shared__ float sm[4];
    for (int e = t; e < deg; e += 256) srcs[e] = inlist[beg + e] & 511;
    __syncthreads();
    for (int idx = t; idx < deg * 4; idx += 256) {
        int e = idx >> 2, q = idx & 3;
        float sc = a_s[srcs[e] * 4 + q] + a_d[n * 4 + q];
        alpha[e][q] = (sc >= 0.f) ? sc : 0.2f * sc;
    }
    __syncthreads();
    if (t < 4) {
        float m = -INFINITY;
        for (int e = 0; e < deg; ++e) m = fmaxf(m, alpha[e][t]);
        if (!isfinite(m)) m = 0.f;
        float s = 0.f;
        for (int e = 0; e < deg; ++e) { float ex = expf(alpha[e][t] - m); alpha[e][t] = ex; s += ex; }
        sm[t] = s + 1e-16f;
    }
    __syncthreads();
    for (int idx = t; idx < deg * 4; idx += 256) {
        int e = idx >> 2, q = idx & 3;
        alpha[e][q] /= sm[q];
    }
    __syncthreads();
    for (int q = 0; q < 4; ++q) {
        float acc = 0.f;
        for (int e = 0; e < deg; ++e) acc += alpha[e][q] * hX[srcs[e] * 1024 + q * 256 + t];
        h1[n * 1024 + q * 256 + t] = fmaxf(acc + bias[q * 256 + t], 0.f);
    }
}

// ---------- K9: GAT2 GEMM + a_s2/a_d2 (2-way K-split, 4 accums) ----------
__global__ __launch_bounds__(256) void k_gat2(const float* __restrict__ h1,
                                              const float* __restrict__ Wf,
                                              const float* __restrict__ asrcf,
                                              const float* __restrict__ adstf,
                                              float* __restrict__ h2,
                                              float* __restrict__ a_s2,
                                              float* __restrict__ a_d2) {
    int n = blockIdx.x, t = threadIdx.x;
    __shared__ float xs[1024];
    __shared__ float hbuf[NCLS];
    __shared__ float sred[256], dred[256];
    for (int c = t; c < 1024; c += 256) xs[c] = h1[n * 1024 + c];
    __syncthreads();
    int cls = t & 127, kh = t >> 7;
    float acc = 0.f;
    if (cls < NCLS) {
        const float* wp = Wf + (kh * 512) * NCLS + cls;
        const float* xp = xs + kh * 512;
        float a0 = 0.f, a1 = 0.f, a2 = 0.f, a3 = 0.f;
        for (int c = 0; c < 512; c += 4) {
            a0 = fmaf(xp[c + 0], wp[(c + 0) * NCLS], a0);
            a1 = fmaf(xp[c + 1], wp[(c + 1) * NCLS], a1);
            a2 = fmaf(xp[c + 2], wp[(c + 2) * NCLS], a2);
            a3 = fmaf(xp[c + 3], wp[(c + 3) * NCLS], a3);
        }
        acc = (a0 + a1) + (a2 + a3);
    }
    if (kh == 0 && cls < NCLS) hbuf[cls] = acc;
    __syncthreads();
    float tot = 0.f;
    int act = (kh == 1 && cls < NCLS);
    if (act) { tot = acc + hbuf[cls]; h2[n * NCLS + cls] = tot; }
    sred[t] = act ? tot * asrcf[cls] : 0.f;
    dred[t] = act ? tot * adstf[cls] : 0.f;
    __syncthreads();
    for (int s = 128; s > 0; s >>= 1) {
        if (t < s) { sred[t] += sred[t + s]; dred[t] += dred[t + s]; }
        __syncthreads();
    }
    if (t == 0) { a_s2[n] = sred[0]; a_d2[n] = dred[0]; }
}

// ---------- K10: GAT2 aggregate -> logits + softmax probs ----------
__global__ void k_aggr2(const float* __restrict__ h2,
                        const float* __restrict__ a_s2, const float* __restrict__ a_d2,
                        const int* __restrict__ offs, const int* __restrict__ inlist,
                        const float* __restrict__ bias,
                        float* __restrict__ logits_out,
                        float* __restrict__ probs_out) {
    int n = blockIdx.x, t = threadIdx.x;
    int beg = offs[n], deg = offs[n + 1] - beg;
    if (deg > 513) deg = 513;
    __shared__ int srcs[520];
    __shared__ float alpha[520];
    __shared__ float red[128];
    __shared__ float smden;
    for (int e = t; e < deg; e += 128) {
        int s = inlist[beg + e] & 511;
        srcs[e] = s;
        float sc = a_s2[s] + a_d2[n];
        alpha[e] = (sc >= 0.f) ? sc : 0.2f * sc;
    }
    __syncthreads();
    if (t == 0) {
        float m = -INFINITY;
        for (int e = 0; e < deg; ++e) m = fmaxf(m, alpha[e]);
        if (!isfinite(m)) m = 0.f;
        float s = 0.f;
        for (int e = 0; e < deg; ++e) { float ex = expf(alpha[e] - m); alpha[e] = ex; s += ex; }
        smden = s + 1e-16f;
    }
    __syncthreads();
    float logit = 0.f;
    if (t < NCLS) {
        float acc = 0.f;
        for (int e = 0; e < deg; ++e) acc += alpha[e] * h2[srcs[e] * NCLS + t];
        logit = acc / smden + bias[t];
        logits_out[n * NCLS + t] = logit;
    }
    red[t] = (t < NCLS) ? logit : -INFINITY; __syncthreads();
    for (int s = 64; s > 0; s >>= 1) { if (t < s) red[t] = fmaxf(red[t], red[t + s]); __syncthreads(); }
    float mx = red[0];
    __syncthreads();
    float ex = (t < NCLS) ? expf(logit - mx) : 0.f;
    red[t] = ex; __syncthreads();
    for (int s = 64; s > 0; s >>= 1) { if (t < s) red[t] += red[t + s]; __syncthreads(); }
    float inv = 1.f / red[0];
    if (t < NCLS) probs_out[n * NCLS + t] = ex * inv;
}

// ---------- launch ----------
extern "C" void kernel_launch(void* const* d_in, const int* in_sizes, int n_in,
                              void* d_out, int out_size, void* d_ws, size_t ws_size,
                              hipStream_t stream) {
    const float* feats   = (const float*)d_in[0];
    const float* boxes   = (const float*)d_in[1];
    const float* repn_w1 = (const float*)d_in[2];
    const float* repn_b1 = (const float*)d_in[3];
    const float* repn_w2 = (const float*)d_in[4];
    const float* repn_b2 = (const float*)d_in[5];
    const float* gat1_w    = (const float*)d_in[6];
    const float* gat1_asrc = (const float*)d_in[7];
    const float* gat1_adst = (const float*)d_in[8];
    const float* gat1_b    = (const float*)d_in[9];
    const float* gat2_w    = (const float*)d_in[10];
    const float* gat2_asrc = (const float*)d_in[11];
    const float* gat2_adst = (const float*)d_in[12];
    const float* gat2_b    = (const float*)d_in[13];
    const int* kp = (const int*)d_in[14];

    float* out = (float*)d_out;
    float* logits_out = out;
    float* probs_out  = out + 512 * NCLS;
    float* rel_out    = out + 2 * 512 * NCLS;

    // Workspace map (floats):
    //  [0,2097152)        pp: 8 x 512x512 p12 partials (pre -> psum); then
    //                     P: 4 x 512x1024 gat1 MFMA partials aliased here (relmm -> epsf);
    //                     hX aliases P0 (epsf -> aggr1); h1 aliases P1 (aggr1 -> gat2)
    //  [2097152,2359296)  ppsum: collapsed p12 result (psum -> relmm)
    //  [2359296,3145728)  prel: 3 rel partials (z=1..3), live relmm -> topk
    //  [3145728,4718592)  bf16 frag arrays: Afh, Afl (262144 floats each),
    //                     Bfh, Bfl (524288 floats each)
    //  [4718592, ...)     h2 / a_s2 / a_d2 / a_s1 / a_d1 / int block
    float* wsf   = (float*)d_ws;
    float* pp    = wsf;
    float* P     = wsf;                 // alias pp (mm1 part launches after psum consumed pp)
    float* hX    = P;
    float* h1    = P + 524288;
    float* ppsum = wsf + 2097152;
    float* prel  = wsf + 2359296;
    ushort* Afh  = (ushort*)(wsf + 3145728);
    ushort* Afl  = (ushort*)(wsf + 3407872);
    ushort* Bfh  = (ushort*)(wsf + 3670016);
    ushort* Bfl  = (ushort*)(wsf + 4194304);
    float* h2    = wsf + 4718592;       // 46592, pad to 47104
    float* a_s2  = wsf + 4765696;
    float* a_d2  = wsf + 4766208;
    float* a_s1  = wsf + 4766720;
    float* a_d1  = wsf + 4768768;
    int* ib      = (int*)(wsf + 4770816);
    int* count   = ib;                  // 512 (zeroed by k_pre)
    int* nbrs    = ib + 1024;           // 4096
    int* offs    = ib + 5120;           // 520
    int* inlist  = ib + 5640;           // 4096

    k_pre<<<dim3(2560), dim3(128), 0, stream>>>(feats, gat1_w, Afh, Afl, Bfh, Bfl,
                                                ib, repn_w1, pp);
    k_psum<<<dim3(256), dim3(256), 0, stream>>>(pp, ppsum);
    k_relmm<<<dim3(1536), dim3(256), 0, stream>>>(ppsum, repn_w1, repn_b1, repn_w2,
                                                  boxes, rel_out, prel,
                                                  Afh, Afl, Bfh, Bfl, P);
    k_topk<<<dim3(512), dim3(64), 0, stream>>>(rel_out, prel, repn_b2, kp,
                                               nbrs, count, rel_out);
    k_epsf<<<dim3(513), dim3(256), 0, stream>>>(P, boxes, gat1_w, gat1_asrc, gat1_adst,
                                                hX, a_s1, a_d1,
                                                count, nbrs, kp, offs, inlist);
    k_aggr1<<<dim3(512), dim3(256), 0, stream>>>(hX, a_s1, a_d1, offs, inlist, gat1_b, h1);
    k_gat2<<<dim3(512), dim3(256), 0, stream>>>(h1, gat2_w, gat2_asrc, gat2_adst,
                                                h2, a_s2, a_d2);
    k_aggr2<<<dim3(512), dim3(128), 0, stream>>>(h2, a_s2, a_d2, offs, inlist, gat2_b,
                                                 logits_out, probs_out);
}

// Round 8
// 172.395 us; speedup vs baseline: 1.1839x; 1.0383x over previous
//
#include <hip/hip_runtime.h>

// Inputs and outputs are float32 (established R1/R3).
#define NCLS 91
#define W1_LD 2052   // repn_w1 row length (2C+4)

typedef __attribute__((ext_vector_type(8))) short short8;   // 8 bf16 (4 VGPRs)
typedef __attribute__((ext_vector_type(4))) float f32x4;    // MFMA C/D

__device__ inline ushort bf16_rne(float x) {
    unsigned u = __float_as_uint(x);
    return (ushort)((u + 0x7fffu + ((u >> 16) & 1u)) >> 16);
}

// ---------- K1: fused conv (bf16 frag split) + p12 partial GEMM ----------
// blocks 0..511:    conv-A  (feats -> Afh/Afl frag layout), b<4 also zero count
// blocks 512..1535: conv-B  (gat1_w K-rows -> Bfh/Bfl frag layout)
// blocks 1536..2559: p12    p_part[z][i][r] = feats[i, z*128:+128].Wcomb[r, z*128:+128]
//                    (Wcomb rows 0..255 = wf1, 256..511 = wf2; decode (8 r,16 i,8 z))
__global__ __launch_bounds__(128) void k_pre(const float* __restrict__ feats,
                                             const float* __restrict__ Wg,
                                             ushort* __restrict__ Afh,
                                             ushort* __restrict__ Afl,
                                             ushort* __restrict__ Bfh,
                                             ushort* __restrict__ Bfl,
                                             int* __restrict__ zero_ints,
                                             const float* __restrict__ w1f,
                                             float* __restrict__ pp) {
    int b = blockIdx.x, tid = threadIdx.x;
    __shared__ float As[64 * 32];   // [k][i]  (p12 branch only)
    __shared__ float Bs[64 * 64];   // [k][r]
    if (b < 1536) {
        // ---- conv branch ----
        if (b < 4) zero_ints[b * 128 + tid] = 0;
        int lane = tid & 63;
        float x[8];
        size_t off;
        ushort *oh, *ol;
        if (b < 512) {   // A: 512 blocks x 128 thr = 65536 lane-items = 32 it x 32 kt x 64
            int g = b * 128 + tid;
            int q = g >> 6;
            int it = q & 31, kt = q >> 5;
            int row = it * 16 + (lane & 15);
            int col0 = kt * 32 + (lane >> 4) * 8;
            const float* src = feats + row * 1024 + col0;
            float4 u0 = *(const float4*)(src);
            float4 u1 = *(const float4*)(src + 4);
            x[0] = u0.x; x[1] = u0.y; x[2] = u0.z; x[3] = u0.w;
            x[4] = u1.x; x[5] = u1.y; x[6] = u1.z; x[7] = u1.w;
            off = ((size_t)(kt * 32 + it) * 64 + lane) * 8;
            oh = Afh; ol = Afl;
        } else {          // B: 1024 blocks = 32 kt x 64 nt x 64 lanes
            int g = (b - 512) * 128 + tid;
            int q = g >> 6;
            int nt = q & 63, kt = q >> 6;
            int col = nt * 16 + (lane & 15);
            int row0 = kt * 32 + (lane >> 4) * 8;
#pragma unroll
            for (int e = 0; e < 8; ++e) x[e] = Wg[(row0 + e) * 1024 + col];
            off = ((size_t)(kt * 64 + nt) * 64 + lane) * 8;
            oh = Bfh; ol = Bfl;
        }
        uint uh[4], ul[4];
#pragma unroll
        for (int p = 0; p < 4; ++p) {
            ushort h0 = bf16_rne(x[2 * p]);
            ushort h1 = bf16_rne(x[2 * p + 1]);
            float f0 = __uint_as_float((unsigned)h0 << 16);
            float f1 = __uint_as_float((unsigned)h1 << 16);
            ushort l0 = bf16_rne(x[2 * p] - f0);
            ushort l1 = bf16_rne(x[2 * p + 1] - f1);
            uh[p] = (uint)h0 | ((uint)h1 << 16);
            ul[p] = (uint)l0 | ((uint)l1 << 16);
        }
        *(uint4*)(oh + off) = make_uint4(uh[0], uh[1], uh[2], uh[3]);
        *(uint4*)(ol + off) = make_uint4(ul[0], ul[1], ul[2], ul[3]);
        return;
    }
    // ---- p12 branch ----
    int bx = b - 1536;
    int r0 = (bx & 7) * 64, i0 = ((bx >> 3) & 15) * 32, z = bx >> 7;
    int tx = tid & 15, ty = tid >> 4;
    float* pout = pp + z * 262144;
    int ai = tid & 31, akq = (tid >> 5) * 16;          // A loader: 4 float4 along k
    int br = tid & 63, bkq = (tid >> 6) * 32;          // B loader: 8 float4 along k
    const float* abase = feats + (i0 + ai) * 1024 + z * 128 + akq;
    int rg = r0 + br;
    const float* bbase = w1f + (rg < 256 ? rg * W1_LD : (rg - 256) * W1_LD + 1024)
                       + z * 128 + bkq;
    float4 av[4], bv[8];
#pragma unroll
    for (int s = 0; s < 4; ++s) av[s] = *(const float4*)(abase + 4 * s);
#pragma unroll
    for (int s = 0; s < 8; ++s) bv[s] = *(const float4*)(bbase + 4 * s);
    float acc[4][4] = {};
    for (int kt = 0; kt < 2; ++kt) {
#pragma unroll
        for (int s = 0; s < 4; ++s) {   // transpose store: lanes distinct ai -> 2-way max
            int k = akq + 4 * s;
            As[(k + 0) * 32 + ai] = av[s].x; As[(k + 1) * 32 + ai] = av[s].y;
            As[(k + 2) * 32 + ai] = av[s].z; As[(k + 3) * 32 + ai] = av[s].w;
        }
#pragma unroll
        for (int s = 0; s < 8; ++s) {   // transpose store: lanes distinct br -> 2-way max
            int k = bkq + 4 * s;
            Bs[(k + 0) * 64 + br] = bv[s].x; Bs[(k + 1) * 64 + br] = bv[s].y;
            Bs[(k + 2) * 64 + br] = bv[s].z; Bs[(k + 3) * 64 + br] = bv[s].w;
        }
        __syncthreads();
        if (kt + 1 < 2) {
#pragma unroll
            for (int s = 0; s < 4; ++s) av[s] = *(const float4*)(abase + 64 + 4 * s);
#pragma unroll
            for (int s = 0; s < 8; ++s) bv[s] = *(const float4*)(bbase + 64 + 4 * s);
        }
#pragma unroll
        for (int k = 0; k < 64; ++k) {
            float4 a4 = *(const float4*)(As + k * 32 + ty * 4);
            float4 b4 = *(const float4*)(Bs + k * 64 + tx * 4);
            acc[0][0] = fmaf(a4.x, b4.x, acc[0][0]); acc[0][1] = fmaf(a4.x, b4.y, acc[0][1]);
            acc[0][2] = fmaf(a4.x, b4.z, acc[0][2]); acc[0][3] = fmaf(a4.x, b4.w, acc[0][3]);
            acc[1][0] = fmaf(a4.y, b4.x, acc[1][0]); acc[1][1] = fmaf(a4.y, b4.y, acc[1][1]);
            acc[1][2] = fmaf(a4.y, b4.z, acc[1][2]); acc[1][3] = fmaf(a4.y, b4.w, acc[1][3]);
            acc[2][0] = fmaf(a4.z, b4.x, acc[2][0]); acc[2][1] = fmaf(a4.z, b4.y, acc[2][1]);
            acc[2][2] = fmaf(a4.z, b4.z, acc[2][2]); acc[2][3] = fmaf(a4.z, b4.w, acc[2][3]);
            acc[3][0] = fmaf(a4.w, b4.x, acc[3][0]); acc[3][1] = fmaf(a4.w, b4.y, acc[3][1]);
            acc[3][2] = fmaf(a4.w, b4.z, acc[3][2]); acc[3][3] = fmaf(a4.w, b4.w, acc[3][3]);
        }
        __syncthreads();
    }
#pragma unroll
    for (int ii = 0; ii < 4; ++ii)
        *(float4*)(pout + (i0 + ty * 4 + ii) * 512 + r0 + tx * 4) =
            make_float4(acc[ii][0], acc[ii][1], acc[ii][2], acc[ii][3]);
}

// ---------- K1b: collapse 8 pp partials -> ppsum (pure streaming, 9 MB) ----------
__global__ __launch_bounds__(256) void k_psum(const float* __restrict__ pp,
                                              float* __restrict__ ppsum) {
    int idx = (blockIdx.x * 256 + threadIdx.x) * 4;
    float4 a = *(const float4*)(pp + idx);
#pragma unroll
    for (int p = 1; p < 8; ++p) {
        float4 v = *(const float4*)(pp + p * 262144 + idx);
        a.x += v.x; a.y += v.y; a.z += v.z; a.w += v.w;
    }
    *(float4*)(ppsum + idx) = a;
}

// ---------- K2: fused rel partials (blocks 0..1023) + GAT1 MFMA GEMM (1024..1535) ----
// rel: h-chunk split 4-way across z; decode (8 j, 32 i, 4 z); ppsum L2-resident.
//      z=0 partial -> r0 (rel_out scratch), z>0 -> prel[z-1]. Final sum+b2 in k_tkep.
// mm1: bf16 MFMA 2-term (hh+hl+lh); decode (16 n, 8 i, 4 z); partial -> P[z].
// LDS shared via union (32 KB -> up to 5 blocks/CU).
__global__ __launch_bounds__(256) void k_relmm(const float* __restrict__ ppsum,
                                               const float* __restrict__ w1f,
                                               const float* __restrict__ b1f,
                                               const float* __restrict__ w2f,
                                               const float* __restrict__ boxesf,
                                               float* __restrict__ r0,
                                               float* __restrict__ prel,
                                               const ushort* __restrict__ Afh,
                                               const ushort* __restrict__ Afl,
                                               const ushort* __restrict__ Bfh,
                                               const ushort* __restrict__ Bfl,
                                               float* __restrict__ P) {
    __shared__ union SM {
        struct { float As1[32 * 17]; float Bs[32 * 64]; float Awg[32 * 4]; float Aw2[32]; } r;
        uint4 buf[2][4][4][64];   // [dbuf][Ah Al Bh Bl][sub][lane]
    } sm;
    int b = blockIdx.x;
    if (b < 1024) {
        // ---- rel branch ----
        int j0 = (b & 7) * 64, i0 = ((b >> 3) & 31) * 16, z = b >> 8;
        int tid = threadIdx.x, tx = tid & 63, ty = tid >> 6;
        float* As1 = sm.r.As1;
        float* Bs  = sm.r.Bs;
        float* Awg = sm.r.Awg;
        float* Aw2 = sm.r.Aw2;
        float4 bj = *(const float4*)(boxesf + (j0 + tx) * 4);
        float g[4][4];
#pragma unroll
        for (int s = 0; s < 4; ++s) {
            float4 bi = *(const float4*)(boxesf + (i0 + ty * 4 + s) * 4);
            g[s][0] = fabsf(bi.x - bj.x); g[s][1] = fabsf(bi.y - bj.y);
            g[s][2] = fabsf(bi.z - bj.z); g[s][3] = fabsf(bi.w - bj.w);
        }
        float acc[4] = {0.f, 0.f, 0.f, 0.f};
        int ali = tid & 15, alh = (tid >> 4) * 4;     // tid<128: one float4 along h
        int blj = tid & 63, blh = (tid >> 6) * 8;     // 2 float4 along h
        for (int c4 = 0; c4 < 2; ++c4) {
            int hb = (z * 2 + c4) * 32;
            if (tid < 128) {
                float4 a4 = *(const float4*)(ppsum + (i0 + ali) * 512 + hb + alh);
                float4 bb = *(const float4*)(b1f + hb + alh);
                As1[(alh + 0) * 17 + ali] = a4.x + bb.x;
                As1[(alh + 1) * 17 + ali] = a4.y + bb.y;
                As1[(alh + 2) * 17 + ali] = a4.z + bb.z;
                As1[(alh + 3) * 17 + ali] = a4.w + bb.w;
            }
#pragma unroll
            for (int s = 0; s < 2; ++s) {
                int h = blh + 4 * s;
                float4 u4 = *(const float4*)(ppsum + (j0 + blj) * 512 + 256 + hb + h);
                Bs[(h + 0) * 64 + blj] = u4.x;
                Bs[(h + 1) * 64 + blj] = u4.y;
                Bs[(h + 2) * 64 + blj] = u4.z;
                Bs[(h + 3) * 64 + blj] = u4.w;
            }
            if (tid < 32) {
                int hg = hb + tid;
                *(float4*)(Awg + tid * 4) = *(const float4*)(w1f + hg * W1_LD + 2048);
                Aw2[tid] = w2f[hg];
            }
            __syncthreads();
#pragma unroll
            for (int hh = 0; hh < 32; ++hh) {
                float4 wg = *(const float4*)(Awg + hh * 4);
                float w2v = Aw2[hh];
                float p2v = Bs[hh * 64 + tx];
                float s0 = As1[hh * 17 + ty * 4 + 0];
                float s1 = As1[hh * 17 + ty * 4 + 1];
                float s2 = As1[hh * 17 + ty * 4 + 2];
                float s3 = As1[hh * 17 + ty * 4 + 3];
                float t0 = s0 + p2v;
                t0 = fmaf(g[0][0], wg.x, t0); t0 = fmaf(g[0][1], wg.y, t0);
                t0 = fmaf(g[0][2], wg.z, t0); t0 = fmaf(g[0][3], wg.w, t0);
                acc[0] = fmaf(w2v, fmaxf(t0, 0.f), acc[0]);
                float t1 = s1 + p2v;
                t1 = fmaf(g[1][0], wg.x, t1); t1 = fmaf(g[1][1], wg.y, t1);
                t1 = fmaf(g[1][2], wg.z, t1); t1 = fmaf(g[1][3], wg.w, t1);
                acc[1] = fmaf(w2v, fmaxf(t1, 0.f), acc[1]);
                float t2 = s2 + p2v;
                t2 = fmaf(g[2][0], wg.x, t2); t2 = fmaf(g[2][1], wg.y, t2);
                t2 = fmaf(g[2][2], wg.z, t2); t2 = fmaf(g[2][3], wg.w, t2);
                acc[2] = fmaf(w2v, fmaxf(t2, 0.f), acc[2]);
                float t3 = s3 + p2v;
                t3 = fmaf(g[3][0], wg.x, t3); t3 = fmaf(g[3][1], wg.y, t3);
                t3 = fmaf(g[3][2], wg.z, t3); t3 = fmaf(g[3][3], wg.w, t3);
                acc[3] = fmaf(w2v, fmaxf(t3, 0.f), acc[3]);
            }
            __syncthreads();
        }
        float* po = (z == 0) ? r0 : (prel + (z - 1) * 262144);
#pragma unroll
        for (int s = 0; s < 4; ++s)
            po[(i0 + ty * 4 + s) * 512 + j0 + tx] = acc[s];
        return;
    }
    // ---- mm1 branch ----
    int m = b - 1024;
    int nt0 = (m & 15) * 4, it0 = ((m >> 4) & 7) * 4, z = m >> 7;
    int t = threadIdx.x, lane = t & 63, w = t >> 6;
    int wr = w >> 1, wc = w & 1, sub = w;
    const uint4* gAh = (const uint4*)Afh;
    const uint4* gAl = (const uint4*)Afl;
    const uint4* gBh = (const uint4*)Bfh;
    const uint4* gBl = (const uint4*)Bfl;
    f32x4 acc[2][2];
    f32x4 zero = {0.f, 0.f, 0.f, 0.f};
    acc[0][0] = zero; acc[0][1] = zero; acc[1][0] = zero; acc[1][1] = zero;
    int ktg = z * 8;
    uint4 rah = gAh[(ktg * 32 + it0 + sub) * 64 + lane];
    uint4 ral = gAl[(ktg * 32 + it0 + sub) * 64 + lane];
    uint4 rbh = gBh[(ktg * 64 + nt0 + sub) * 64 + lane];
    uint4 rbl = gBl[(ktg * 64 + nt0 + sub) * 64 + lane];
    for (int kk = 0; kk < 8; ++kk) {
        int cur = kk & 1;
        sm.buf[cur][0][sub][lane] = rah;
        sm.buf[cur][1][sub][lane] = ral;
        sm.buf[cur][2][sub][lane] = rbh;
        sm.buf[cur][3][sub][lane] = rbl;
        __syncthreads();
        if (kk < 7) {
            int kn = ktg + kk + 1;
            rah = gAh[(kn * 32 + it0 + sub) * 64 + lane];
            ral = gAl[(kn * 32 + it0 + sub) * 64 + lane];
            rbh = gBh[(kn * 64 + nt0 + sub) * 64 + lane];
            rbl = gBl[(kn * 64 + nt0 + sub) * 64 + lane];
        }
        short8 ah[2], al[2], bh[2], bl[2];
#pragma unroll
        for (int i = 0; i < 2; ++i) {
            ah[i] = *(const short8*)&sm.buf[cur][0][2 * wr + i][lane];
            al[i] = *(const short8*)&sm.buf[cur][1][2 * wr + i][lane];
            bh[i] = *(const short8*)&sm.buf[cur][2][2 * wc + i][lane];
            bl[i] = *(const short8*)&sm.buf[cur][3][2 * wc + i][lane];
        }
#pragma unroll
        for (int i = 0; i < 2; ++i)
#pragma unroll
            for (int j = 0; j < 2; ++j) {
                acc[i][j] = __builtin_amdgcn_mfma_f32_16x16x32_bf16(ah[i], bh[j], acc[i][j], 0, 0, 0);
                acc[i][j] = __builtin_amdgcn_mfma_f32_16x16x32_bf16(ah[i], bl[j], acc[i][j], 0, 0, 0);
                acc[i][j] = __builtin_amdgcn_mfma_f32_16x16x32_bf16(al[i], bh[j], acc[i][j], 0, 0, 0);
            }
        __syncthreads();
    }
    float* outp = P + z * 524288;
#pragma unroll
    for (int i = 0; i < 2; ++i)
#pragma unroll
        for (int j = 0; j < 2; ++j) {
            int rbase = (it0 + 2 * wr + i) * 16 + (lane >> 4) * 4;
            int c = (nt0 + 2 * wc + j) * 16 + (lane & 15);
#pragma unroll
            for (int r = 0; r < 4; ++r)
                outp[(size_t)(rbase + r) * 1024 + c] = acc[i][j][r];
        }
}

// ---------- K3: fused topk (blocks 512..1023) + GAT1 epilogue (blocks 0..511) ----------
// gat1ep depends only on P (k_relmm); topk depends only on rel partials (k_relmm).
// Merging hides gat1ep's ~5 us under topk and removes one dispatch.
__global__ __launch_bounds__(256) void k_tkep(const float* __restrict__ P,
                                              const float* __restrict__ boxesf,
                                              const float* __restrict__ Wg,
                                              const float* __restrict__ asrcf,
                                              const float* __restrict__ adstf,
                                              float* __restrict__ hX,
                                              float* __restrict__ a_s1,
                                              float* __restrict__ a_d1,
                                              const float* __restrict__ r0,
                                              const float* __restrict__ prel,
                                              const float* __restrict__ b2f,
                                              const int* __restrict__ kp,
                                              int* __restrict__ nbrs,
                                              int* __restrict__ count,
                                              float* __restrict__ rel_out) {
    __shared__ float rs[4][4], rd[4][4];
    int t = threadIdx.x;
    if (blockIdx.x >= 512) {
        // ---- topk branch: sum 4 rel partials + b2 -> rel_out; per-row top-(k+1) ----
        if (t >= 64) return;   // single wave; no __syncthreads in this branch
        int i = blockIdx.x - 512, lane = t;
        int k = *kp;
        float b2v = b2f[0];
        float v[8]; int ids[8];
        for (int q = 0; q < 8; ++q) {
            int j = lane + 64 * q;
            float val = r0[i * 512 + j] + prel[i * 512 + j]
                      + prel[262144 + i * 512 + j] + prel[524288 + i * 512 + j] + b2v;
            rel_out[i * 512 + j] = val;   // same thread reads then writes this slot
            v[q] = val;
            ids[q] = j;
        }
        for (int pick = 0; pick < k + 1; ++pick) {
            float bv = -INFINITY; int bidx = 1 << 30;
            for (int q = 0; q < 8; ++q)
                if (v[q] > bv || (v[q] == bv && ids[q] < bidx)) { bv = v[q]; bidx = ids[q]; }
            for (int off = 32; off > 0; off >>= 1) {
                float ov = __shfl_down(bv, off);
                int oi = __shfl_down(bidx, off);
                if (ov > bv || (ov == bv && oi < bidx)) { bv = ov; bidx = oi; }
            }
            bv = __shfl(bv, 0); bidx = __shfl(bidx, 0);
            if (pick >= 1 && lane == 0) {
                nbrs[i * 8 + (pick - 1)] = bidx;
                atomicAdd(&count[bidx], 1);
            }
            for (int q = 0; q < 8; ++q) if (ids[q] == bidx) v[q] = -INFINITY;
        }
        if (lane == 0) atomicAdd(&count[i], 1);
        return;
    }
    // ---- gat1ep branch: sum 4 partials + geom rows + a_s1/a_d1 ----
    int i = blockIdx.x;
    const float* P0 = P;
    const float* P1 = P + 524288;
    const float* P2 = P + 1048576;
    const float* P3 = P + 1572864;
    float4 bx = *(const float4*)(boxesf + i * 4);
    float g0 = bx.x / 800.f, g1 = bx.y / 800.f;
    float g2 = bx.z / 800.f - g0, g3 = bx.w / 800.f - g1;
    float ps[4], pd[4];
#pragma unroll
    for (int q = 0; q < 4; ++q) {
        int c = q * 256 + t;
        float v = P0[i * 1024 + c] + P1[i * 1024 + c] + P2[i * 1024 + c] + P3[i * 1024 + c];
        v = fmaf(g0, Wg[1024 * 1024 + c], v);
        v = fmaf(g1, Wg[1025 * 1024 + c], v);
        v = fmaf(g2, Wg[1026 * 1024 + c], v);
        v = fmaf(g3, Wg[1027 * 1024 + c], v);
        hX[i * 1024 + c] = v;          // in-place over P0 row i (same thread RAW only)
        ps[q] = v * asrcf[c];
        pd[q] = v * adstf[c];
    }
    int wid = t >> 6;
#pragma unroll
    for (int off = 32; off > 0; off >>= 1) {
#pragma unroll
        for (int q = 0; q < 4; ++q) {
            ps[q] += __shfl_down(ps[q], off);
            pd[q] += __shfl_down(pd[q], off);
        }
    }
    if ((t & 63) == 0) {
#pragma unroll
        for (int q = 0; q < 4; ++q) { rs[wid][q] = ps[q]; rd[wid][q] = pd[q]; }
    }
    __syncthreads();
    if (t < 4)
        a_s1[i * 4 + t] = rs[0][t] + rs[1][t] + rs[2][t] + rs[3][t];
    else if (t < 8) {
        int q = t - 4;
        a_d1[i * 4 + q] = rd[0][q] + rd[1][q] + rd[2][q] + rd[3][q];
    }
}

// ---------- K4: exclusive scan + fill in-edge lists (fused, 1 block, LDS cursor) ----------
__global__ void k_scanfill(const int* __restrict__ count, const int* __restrict__ nbrs,
                           const int* __restrict__ kp,
                           int* __restrict__ offs, int* __restrict__ inlist) {
    __shared__ int s[512];
    __shared__ int excl[512];
    __shared__ int cur[512];
    int t = threadIdx.x;
    int c = count[t];
    s[t] = c; cur[t] = 0;
    __syncthreads();
    for (int off = 1; off < 512; off <<= 1) {
        int v = (t >= off) ? s[t - off] : 0;
        __syncthreads();
        s[t] += v;
        __syncthreads();
    }
    offs[t + 1] = s[t];
    if (t == 0) offs[0] = 0;
    excl[t] = s[t] - c;
    __syncthreads();
    int k = *kp;
    for (int q = 0; q < k; ++q) {
        int d = nbrs[t * 8 + q] & 511;
        int pos = atomicAdd(&cur[d], 1);
        inlist[excl[d] + pos] = t;
    }
    int pos = atomicAdd(&cur[t], 1);
    inlist[excl[t] + pos] = t;
}

// ---------- K5: fused GAT1 aggregate + GAT2 GEMM (per-node; h1 row stays in LDS) ----------
__global__ __launch_bounds__(256) void k_ag12(const float* __restrict__ hX,
                                              const float* __restrict__ a_s,
                                              const float* __restrict__ a_d,
                                              const int* __restrict__ offs,
                                              const int* __restrict__ inlist,
                                              const float* __restrict__ bias1,
                                              const float* __restrict__ Wf,
                                              const float* __restrict__ asrcf,
                                              const float* __restrict__ adstf,
                                              float* __restrict__ h2,
                                              float* __restrict__ a_s2,
                                              float* __restrict__ a_d2) {
    int n = blockIdx.x, t = threadIdx.x;
    int beg = offs[n], deg = offs[n + 1] - beg;
    if (deg > 513) deg = 513;
    __shared__ int srcs[520];
    __shared__ float alpha[520][4];
    __shared__ float sm[4];
    __shared__ float xs[1024];
    __shared__ float hbuf[NCLS];
    __shared__ float sred[256], dred[256];
    // ---- aggr1 into xs (LDS) ----
    for (int e = t; e < deg; e += 256) srcs[e] = inlist[beg + e] & 511;
    __syncthreads();
    for (int idx = t; idx < deg * 4; idx += 256) {
        int e = idx >> 2, q = idx & 3;
        float sc = a_s[srcs[e] * 4 + q] + a_d[n * 4 + q];
        alpha[e][q] = (sc >= 0.f) ? sc : 0.2f * sc;
    }
    __syncthreads();
    if (t < 4) {
        float m = -INFINITY;
        for (int e = 0; e < deg; ++e) m = fmaxf(m, alpha[e][t]);
        if (!isfinite(m)) m = 0.f;
        float s = 0.f;
        for (int e = 0; e < deg; ++e) { float ex = expf(alpha[e][t] - m); alpha[e][t] = ex; s += ex; }
        sm[t] = s + 1e-16f;
    }
    __syncthreads();
    for (int idx = t; idx < deg * 4; idx += 256) {
        int e = idx >> 2, q = idx & 3;
        alpha[e][q] /= sm[q];
    }
    __syncthreads();
    for (int q = 0; q < 4; ++q) {
        float acc = 0.f;
        for (int e = 0; e < deg; ++e) acc += alpha[e][q] * hX[srcs[e] * 1024 + q * 256 + t];
        xs[q * 256 + t] = fmaxf(acc + bias1[q * 256 + t], 0.f);
    }
    __syncthreads();
    // ---- gat2 using xs (no global h1 round-trip) ----
    int cls = t & 127, kh = t >> 7;
    float acc = 0.f;
    if (cls < NCLS) {
        const float* wp = Wf + (kh * 512) * NCLS + cls;
        const float* xp = xs + kh * 512;
        float a0 = 0.f, a1 = 0.f, a2 = 0.f, a3 = 0.f;
        for (int c = 0; c < 512; c += 4) {
            a0 = fmaf(xp[c + 0], wp[(c + 0) * NCLS], a0);
            a1 = fmaf(xp[c + 1], wp[(c + 1) * NCLS], a1);
            a2 = fmaf(xp[c + 2], wp[(c + 2) * NCLS], a2);
            a3 = fmaf(xp[c + 3], wp[(c + 3) * NCLS], a3);
        }
        acc = (a0 + a1) + (a2 + a3);
    }
    if (kh == 0 && cls < NCLS) hbuf[cls] = acc;
    __syncthreads();
    float tot = 0.f;
    int act = (kh == 1 && cls < NCLS);
    if (act) { tot = acc + hbuf[cls]; h2[n * NCLS + cls] = tot; }
    sred[t] = act ? tot * asrcf[cls] : 0.f;
    dred[t] = act ? tot * adstf[cls] : 0.f;
    __syncthreads();
    for (int s = 128; s > 0; s >>= 1) {
        if (t < s) { sred[t] += sred[t + s]; dred[t] += dred[t + s]; }
        __syncthreads();
    }
    if (t == 0) { a_s2[n] = sred[0]; a_d2[n] = dred[0]; }
}

// ---------- K6: GAT2 aggregate -> logits + softmax probs ----------
__global__ void k_aggr2(const float* __restrict__ h2,
                        const float* __restrict__ a_s2, const float* __restrict__ a_d2,
                        const int* __restrict__ offs, const int* __restrict__ inlist,
                        const float* __restrict__ bias,
                        float* __restrict__ logits_out,
                        float* __restrict__ probs_out) {
    int n = blockIdx.x, t = threadIdx.x;
    int beg = offs[n], deg = offs[n + 1] - beg;
    if (deg > 513) deg = 513;
    __shared__ int srcs[520];
    __shared__ float alpha[520];
    __shared__ float red[128];
    __shared__ float smden;
    for (int e = t; e < deg; e += 128) {
        int s = inlist[beg + e] & 511;
        srcs[e] = s;
        float sc = a_s2[s] + a_d2[n];
        alpha[e] = (sc >= 0.f) ? sc : 0.2f * sc;
    }
    __syncthreads();
    if (t == 0) {
        float m = -INFINITY;
        for (int e = 0; e < deg; ++e) m = fmaxf(m, alpha[e]);
        if (!isfinite(m)) m = 0.f;
        float s = 0.f;
        for (int e = 0; e < deg; ++e) { float ex = expf(alpha[e] - m); alpha[e] = ex; s += ex; }
        smden = s + 1e-16f;
    }
    __syncthreads();
    float logit = 0.f;
    if (t < NCLS) {
        float acc = 0.f;
        for (int e = 0; e < deg; ++e) acc += alpha[e] * h2[srcs[e] * NCLS + t];
        logit = acc / smden + bias[t];
        logits_out[n * NCLS + t] = logit;
    }
    red[t] = (t < NCLS) ? logit : -INFINITY; __syncthreads();
    for (int s = 64; s > 0; s >>= 1) { if (t < s) red[t] = fmaxf(red[t], red[t + s]); __syncthreads(); }
    float mx = red[0];
    __syncthreads();
    float ex = (t < NCLS) ? expf(logit - mx) : 0.f;
    red[t] = ex; __syncthreads();
    for (int s = 64; s > 0; s >>= 1) { if (t < s) red[t] += red[t + s]; __syncthreads(); }
    float inv = 1.f / red[0];
    if (t < NCLS) probs_out[n * NCLS + t] = ex * inv;
}

// ---------- launch ----------
extern "C" void kernel_launch(void* const* d_in, const int* in_sizes, int n_in,
                              void* d_out, int out_size, void* d_ws, size_t ws_size,
                              hipStream_t stream) {
    const float* feats   = (const float*)d_in[0];
    const float* boxes   = (const float*)d_in[1];
    const float* repn_w1 = (const float*)d_in[2];
    const float* repn_b1 = (const float*)d_in[3];
    const float* repn_w2 = (const float*)d_in[4];
    const float* repn_b2 = (const float*)d_in[5];
    const float* gat1_w    = (const float*)d_in[6];
    const float* gat1_asrc = (const float*)d_in[7];
    const float* gat1_adst = (const float*)d_in[8];
    const float* gat1_b    = (const float*)d_in[9];
    const float* gat2_w    = (const float*)d_in[10];
    const float* gat2_asrc = (const float*)d_in[11];
    const float* gat2_adst = (const float*)d_in[12];
    const float* gat2_b    = (const float*)d_in[13];
    const int* kp = (const int*)d_in[14];

    float* out = (float*)d_out;
    float* logits_out = out;
    float* probs_out  = out + 512 * NCLS;
    float* rel_out    = out + 2 * 512 * NCLS;

    // Workspace map (floats):
    //  [0,2097152)        pp: 8 x 512x512 p12 partials (pre -> psum); then
    //                     P: 4 x 512x1024 gat1 MFMA partials aliased here (relmm -> tkep);
    //                     hX aliases P0 (tkep -> ag12)
    //  [2097152,2359296)  ppsum: collapsed p12 result (psum -> relmm)
    //  [2359296,3145728)  prel: 3 rel partials (z=1..3), live relmm -> tkep
    //  [3145728,4718592)  bf16 frag arrays: Afh, Afl (262144 floats each),
    //                     Bfh, Bfl (524288 floats each)
    //  [4718592, ...)     h2 / a_s2 / a_d2 / a_s1 / a_d1 / int block
    float* wsf   = (float*)d_ws;
    float* pp    = wsf;
    float* P     = wsf;                 // alias pp (mm1 part launches after psum consumed pp)
    float* hX    = P;
    float* ppsum = wsf + 2097152;
    float* prel  = wsf + 2359296;
    ushort* Afh  = (ushort*)(wsf + 3145728);
    ushort* Afl  = (ushort*)(wsf + 3407872);
    ushort* Bfh  = (ushort*)(wsf + 3670016);
    ushort* Bfl  = (ushort*)(wsf + 4194304);
    float* h2    = wsf + 4718592;       // 46592, pad to 47104
    float* a_s2  = wsf + 4765696;
    float* a_d2  = wsf + 4766208;
    float* a_s1  = wsf + 4766720;
    float* a_d1  = wsf + 4768768;
    int* ib      = (int*)(wsf + 4770816);
    int* count   = ib;                  // 512 (zeroed by k_pre)
    int* nbrs    = ib + 1024;           // 4096
    int* offs    = ib + 5120;           // 520
    int* inlist  = ib + 5640;           // 4096

    k_pre<<<dim3(2560), dim3(128), 0, stream>>>(feats, gat1_w, Afh, Afl, Bfh, Bfl,
                                                ib, repn_w1, pp);
    k_psum<<<dim3(256), dim3(256), 0, stream>>>(pp, ppsum);
    k_relmm<<<dim3(1536), dim3(256), 0, stream>>>(ppsum, repn_w1, repn_b1, repn_w2,
                                                  boxes, rel_out, prel,
                                                  Afh, Afl, Bfh, Bfl, P);
    k_tkep<<<dim3(1024), dim3(256), 0, stream>>>(P, boxes, gat1_w, gat1_asrc, gat1_adst,
                                                 hX, a_s1, a_d1,
                                                 rel_out, prel, repn_b2, kp,
                                                 nbrs, count, rel_out);
    k_scanfill<<<dim3(1), dim3(512), 0, stream>>>(count, nbrs, kp, offs, inlist);
    k_ag12<<<dim3(512), dim3(256), 0, stream>>>(hX, a_s1, a_d1, offs, inlist, gat1_b,
                                                gat2_w, gat2_asrc, gat2_adst,
                                                h2, a_s2, a_d2);
    k_aggr2<<<dim3(512), dim3(128), 0, stream>>>(h2, a_s2, a_d2, offs, inlist, gat2_b,
                                                 logits_out, probs_out);
}